// Round 6
// baseline (2277.758 us; speedup 1.0000x reference)
//
#include <hip/hip_runtime.h>
#include <hip/hip_bf16.h>
#include <stdint.h>

typedef __attribute__((ext_vector_type(8))) short short8v;  // MFMA bf16 A/B frag (guide §3)
typedef __attribute__((ext_vector_type(4))) float float4v;  // MFMA C/D frag

#define DEVI __device__ __forceinline__

constexpr int BATCH = 256;
constexpr int NN   = 81;
constexpr int HID  = 96;
constexpr int NOUT = 9;
constexpr int BLOCK = 512;
constexpr int LDA = 100;   // LDS f32 row stride: mult of 4 (16B-aligned rows) + bank rotation

// LDS float offsets (frag-read buffers stride LDA; Xg stride 96). Pad-row frag reads
// (rows 81..95) spill into the NEXT region - harmless finite garbage, C rows masked on write.
constexpr int OFF_H  = 0;
constexpr int OFF_AP = 8100;    // 81*100
constexpr int OFF_BV = 16200;
constexpr int OFF_MS = 24300;
constexpr int OFF_XG = 32400;   // 81*96
constexpr int SMEM_F = 40176;   // 160,704 B <= 163,840

// packed weights in d_ws (shorts). Per matrix: hi tiles [(ct*3+kt)*512 + lane*8 + j],
// lo plane at +ntiles*512. ALL source matrices are [K rows][C cols] row-major.
// rel_w0 / g_w0 are 192x96 (K=192): packed as TWO 96x96 halves (rows 0..95 / 96..191).
constexpr int W_REL0A = 0;       // rel_w0 rows 0..95   (self proj)
constexpr int W_REL0B = 18432;   // rel_w0 rows 96..191 (neighbor proj)
constexpr int W_REL1  = 36864;
constexpr int W_REL2  = 55296;
constexpr int W_G0B   = 73728;   // g_w0 rows 96..191
constexpr int W_G1    = 92160;
constexpr int W_G2    = 110592;
constexpr int W_IH    = 129024;  // 96x384, 72 tiles
constexpr int W_HH    = 202752;
constexpr int W_R0    = 276480;
constexpr int W_R1    = 294912;
constexpr int W_R2    = 313344;  // 96x16 (cols 9..15 zero), 3 tiles
constexpr int W_IN1   = 316416;
constexpr int W_IN2   = 334848;
constexpr int W_G0A   = 353280;  // g_w0 rows 0..95 ; end 371,712 shorts = 743,424 B

DEVI float sigm(float x)  { return 1.f / (1.f + __expf(-x)); }
DEVI float tanh_(float x) { return 1.f - 2.f / (__expf(2.f * x) + 1.f); }

// hi = truncate-to-bf16 (exact residual in f32), lo = RNE-bf16(x - hi): rel err ~2^-15
DEVI short bfhi(float x) { union { float f; unsigned u; } v; v.f = x; return (short)(v.u >> 16); }
DEVI float fromBits(short s) { union { unsigned u; float f; } v; v.u = ((unsigned)(unsigned short)s) << 16; return v.f; }
DEVI short bfrne(float x) {
  union { float f; unsigned u; } v; v.f = x;
  unsigned r = v.u + 0x7fffu + ((v.u >> 16) & 1u);
  return (short)(r >> 16);
}
DEVI void split1(float x, short& h, short& l) { h = bfhi(x); l = bfrne(x - fromBits(h)); }

DEVI void splitFrag(const float* p, short8v& hv, short8v& lv) {
  const float4 a = *reinterpret_cast<const float4*>(p);
  const float4 b = *reinterpret_cast<const float4*>(p + 4);
  short h, l;
  split1(a.x, h, l); hv[0] = h; lv[0] = l;
  split1(a.y, h, l); hv[1] = h; lv[1] = l;
  split1(a.z, h, l); hv[2] = h; lv[2] = l;
  split1(a.w, h, l); hv[3] = h; lv[3] = l;
  split1(b.x, h, l); hv[4] = h; lv[4] = l;
  split1(b.y, h, l); hv[5] = h; lv[5] = l;
  split1(b.z, h, l); hv[6] = h; lv[6] = l;
  split1(b.w, h, l); hv[7] = h; lv[7] = l;
}
// t0 = relu(Ap_row + Bv_row), split
DEVI void splitFragPair(const float* ap, const float* bp, short8v& hv, short8v& lv) {
  const float4 a0 = *reinterpret_cast<const float4*>(ap);
  const float4 a1 = *reinterpret_cast<const float4*>(ap + 4);
  const float4 b0 = *reinterpret_cast<const float4*>(bp);
  const float4 b1 = *reinterpret_cast<const float4*>(bp + 4);
  float v[8] = { a0.x + b0.x, a0.y + b0.y, a0.z + b0.z, a0.w + b0.w,
                 a1.x + b1.x, a1.y + b1.y, a1.z + b1.z, a1.w + b1.w };
  short h, l;
  #pragma unroll
  for (int i = 0; i < 8; ++i) { split1(fmaxf(v[i], 0.f), h, l); hv[i] = h; lv[i] = l; }
}

DEVI float4v mfma3(short8v ah, short8v al, short8v bh, short8v bl, float4v acc) {
  acc = __builtin_amdgcn_mfma_f32_16x16x32_bf16(ah, bh, acc, 0, 0, 0);
  acc = __builtin_amdgcn_mfma_f32_16x16x32_bf16(al, bh, acc, 0, 0, 0);
  acc = __builtin_amdgcn_mfma_f32_16x16x32_bf16(ah, bl, acc, 0, 0, 0);
  return acc;
}

// e-th Sudoku peer of node n (order-free: message sum is permutation-invariant)
DEVI int nbr_of(int n, int e) {
  const int r = n / 9, c = n - 9 * r;
  if (e < 8)  { int cc = c + 1 + e;  if (cc >= 9) cc -= 9; return r * 9 + cc; }
  if (e < 16) { int rr = r + e - 7;  if (rr >= 9) rr -= 9; return rr * 9 + c; }
  const int q = e - 16, dr = 1 + (q >> 1), dc = 1 + (q & 1);
  const int rm = r % 3, cm = c % 3;
  int rr = r - rm + rm + dr; rr -= (rm + dr >= 3) ? 3 : 0;
  int cc = c - cm + cm + dc; cc -= (cm + dc >= 3) ? 3 : 0;
  return rr * 9 + cc;
}

// ---------------- weight pack kernel ----------------
__global__ __launch_bounds__(64)
void pack_kernel(const float* rel_w0, const float* rel_w1, const float* rel_w2,
                 const float* g_w0, const float* g_w1, const float* g_w2,
                 const float* wih, const float* whh,
                 const float* r_w0, const float* r_w1, const float* r_w2,
                 const float* in_w1, const float* in_w2, short* ws)
{
  const int lane = threadIdx.x;
  const int blk = blockIdx.x;
  const int starts[16] = {0,18,36,54,72,90,108,126,198,270,288,306,309,327,345,363};
  int mi = 0;
  while (blk >= starts[mi + 1]) ++mi;
  const int tt = blk - starts[mi];
  const int ntile = starts[mi + 1] - starts[mi];
  const float* src; int C = 96, row0 = 0, off;
  switch (mi) {
    case 0:  src = rel_w0; off = W_REL0A; break;            // rel_w0[0:96]   (192x96!)
    case 1:  src = rel_w0; row0 = 96; off = W_REL0B; break; // rel_w0[96:192]
    case 2:  src = rel_w1; off = W_REL1; break;
    case 3:  src = rel_w2; off = W_REL2; break;
    case 4:  src = g_w0; row0 = 96; off = W_G0B; break;
    case 5:  src = g_w1; off = W_G1; break;
    case 6:  src = g_w2; off = W_G2; break;
    case 7:  src = wih; C = 384; off = W_IH; break;
    case 8:  src = whh; C = 384; off = W_HH; break;
    case 9:  src = r_w0; off = W_R0; break;
    case 10: src = r_w1; off = W_R1; break;
    case 11: src = r_w2; C = 9; off = W_R2; break;
    case 12: src = in_w1; off = W_IN1; break;
    case 13: src = in_w2; off = W_IN2; break;
    default: src = g_w0; off = W_G0A; break;
  }
  const int kt = tt % 3, ct = tt / 3;
  const int q = lane >> 4, r = lane & 15;
  const int c = ct * 16 + r;
  short* hd = ws + off + tt * 512 + lane * 8;
  short* ld = hd + ntile * 512;
  #pragma unroll
  for (int j = 0; j < 8; ++j) {
    const int k = row0 + kt * 32 + q * 8 + j;
    float w = (c < C) ? src[k * C + c] : 0.f;
    short h, l; split1(w, h, l);
    hd[j] = h; ld[j] = l;
  }
}

// ---------------- generic node-GEMM stage: dst[81 x (CT*16)] = act(A[81x96] @ W + ...) ----------------
DEVI void stage96(float* sm, int aOff, const short* WS, int wOff, int wTiles, int CT,
                  const float* bias, float bscale, bool relu, bool xgAdd,
                  float* dst, int dstLD, int wave, int lane)
{
  const int rl = lane & 15, q = lane >> 4;
  const int plane = wTiles * 512;
  for (int t = wave; t < 3 * CT; t += 8) {
    const int rtp = t % 3, ct = t / 3;
    short8v ah[2][3], al[2][3];
    #pragma unroll
    for (int sub = 0; sub < 2; ++sub) {
      const int row = rtp * 32 + sub * 16 + rl;
      const float* ap = &sm[aOff + row * LDA + q * 8];
      #pragma unroll
      for (int kt = 0; kt < 3; ++kt) splitFrag(ap + kt * 32, ah[sub][kt], al[sub][kt]);
    }
    float4v acc0 = {0.f, 0.f, 0.f, 0.f}, acc1 = {0.f, 0.f, 0.f, 0.f};
    #pragma unroll
    for (int kt = 0; kt < 3; ++kt) {
      const short* bp = WS + wOff + (ct * 3 + kt) * 512 + lane * 8;
      const short8v bh = *reinterpret_cast<const short8v*>(bp);
      const short8v bl = *reinterpret_cast<const short8v*>(bp + plane);
      acc0 = mfma3(ah[0][kt], al[0][kt], bh, bl, acc0);
      acc1 = mfma3(ah[1][kt], al[1][kt], bh, bl, acc1);
    }
    const int col = ct * 16 + rl;
    #pragma unroll
    for (int sub = 0; sub < 2; ++sub) {
      #pragma unroll
      for (int j = 0; j < 4; ++j) {
        const int row = rtp * 32 + sub * 16 + q * 4 + j;
        if (row < NN) {
          float v = sub ? acc1[j] : acc0[j];
          if (bias)  v += bias[col] * bscale;
          if (xgAdd) v += sm[OFF_XG + row * 96 + col];
          if (relu)  v = fmaxf(v, 0.f);
          dst[row * dstLD + col] = v;
        }
      }
    }
  }
}

// ---------------- main kernel ----------------
// __launch_bounds__(512, 1): 1 block/CU (LDS-capped anyway) -> 256-VGPR budget.
// (512, 2) was interpreted as 2 blocks/CU -> 128-VGPR cap -> 650 MB scratch spill (r5 counters).
__global__ __launch_bounds__(BLOCK, 1)
void rrn_kernel(const int* __restrict__ grids, const int* __restrict__ itersp,
                const float* __restrict__ emb, const float* __restrict__ in_w0,
                const float* __restrict__ in_b0, const float* __restrict__ in_b1,
                const float* __restrict__ in_b2,
                const float* __restrict__ rel_b0, const float* __restrict__ rel_b1,
                const float* __restrict__ rel_b2,
                const float* __restrict__ g_b0, const float* __restrict__ g_b1,
                const float* __restrict__ g_b2,
                const float* __restrict__ bih, const float* __restrict__ bhh,
                const float* __restrict__ r_b0, const float* __restrict__ r_b1,
                const float* __restrict__ r_b2,
                const float* __restrict__ c0, const short* __restrict__ WS,
                float* __restrict__ out)
{
  __shared__ float sm[SMEM_F];
  const int b = blockIdx.x, tid = threadIdx.x;
  const int wave = tid >> 6, lane = tid & 63;
  const int rl = lane & 15, q = lane >> 4;
  const int iters = itersp[0];

  // LSTM cell state in registers: unit u = wave + ui*8 (u<36): rt=u%6, cc=u/6
  float creg[5][4];
  #pragma unroll
  for (int ui = 0; ui < 5; ++ui) {
    const int u = wave + ui * 8;
    if (u < 36) {
      const int rt = u % 6, cc = u / 6;
      #pragma unroll
      for (int j = 0; j < 4; ++j) {
        const int row = rt * 16 + q * 4 + j, col = cc * 16 + rl;
        creg[ui][j] = (row < NN) ? c0[(size_t)b * NN * HID + row * HID + col] : 0.f;
      }
    }
  }

  // ---- prologue: embed L0 (VALU, K=16) then MFMA stages ----
  for (int t = tid; t < NN * HID; t += BLOCK) {
    const int n = t / HID, col = t - n * HID;
    const int g = grids[b * NN + n];
    float acc = in_b0[col];
    #pragma unroll
    for (int k = 0; k < 16; ++k) acc += emb[g * 16 + k] * in_w0[k * HID + col];
    sm[OFF_AP + n * LDA + col] = fmaxf(acc, 0.f);
  }
  __syncthreads();
  stage96(sm, OFF_AP, WS, W_IN1, 18, 6, in_b1, 1.f, true,  false, &sm[OFF_BV], LDA, wave, lane);
  __syncthreads();
  stage96(sm, OFF_BV, WS, W_IN2, 18, 6, in_b2, 1.f, false, false, &sm[OFF_H],  LDA, wave, lane);
  __syncthreads();
  stage96(sm, OFF_H,  WS, W_G0A, 18, 6, g_b0,  1.f, false, false, &sm[OFF_XG], 96,  wave, lane);
  __syncthreads();

  for (int it = 0; it < iters; ++it) {
    // phase 1: zero Msum; Ap = h@rel_w0[0:96] + rel_b0 ; Bv = h@rel_w0[96:192]
    for (int i = tid; i < 8100; i += BLOCK) sm[OFF_MS + i] = 0.f;
    stage96(sm, OFF_H, WS, W_REL0A, 18, 6, rel_b0, 1.f, false, false, &sm[OFF_AP], LDA, wave, lane);
    stage96(sm, OFF_H, WS, W_REL0B, 18, 6, nullptr, 0.f, false, false, &sm[OFF_BV], LDA, wave, lane);
    __syncthreads();

    // phase 2: pair GEMM, 26 wave-private groups of 64 pair-rows; Msum via LDS atomics
    for (int g4 = wave; g4 < 26; g4 += 8) {
      short8v ah[4][3], al[4][3];
      #pragma unroll
      for (int sub = 0; sub < 4; ++sub) {
        const int row = g4 * 64 + sub * 16 + rl;
        if (row < 1620) {
          const int n = row / 20, e = row - 20 * n, m = nbr_of(n, e);
          const float* ap = &sm[OFF_AP + n * LDA + q * 8];
          const float* bp = &sm[OFF_BV + m * LDA + q * 8];
          #pragma unroll
          for (int kt = 0; kt < 3; ++kt)
            splitFragPair(ap + kt * 32, bp + kt * 32, ah[sub][kt], al[sub][kt]);
        } else {
          const short8v z = {0,0,0,0,0,0,0,0};
          #pragma unroll
          for (int kt = 0; kt < 3; ++kt) { ah[sub][kt] = z; al[sub][kt] = z; }
        }
      }
      for (int ct = 0; ct < 6; ++ct) {
        const float rb1c = rel_b1[ct * 16 + rl];   // L1-resident, avoids scratch array
        short8v bh[3], bl[3];
        #pragma unroll
        for (int kt = 0; kt < 3; ++kt) {
          const short* bp = WS + W_REL1 + (ct * 3 + kt) * 512 + lane * 8;
          bh[kt] = *reinterpret_cast<const short8v*>(bp);
          bl[kt] = *reinterpret_cast<const short8v*>(bp + 18 * 512);
        }
        float4v acc[4] = {{0,0,0,0},{0,0,0,0},{0,0,0,0},{0,0,0,0}};
        #pragma unroll
        for (int sub = 0; sub < 4; ++sub)
          #pragma unroll
          for (int kt = 0; kt < 3; ++kt)
            acc[sub] = mfma3(ah[sub][kt], al[sub][kt], bh[kt], bl[kt], acc[sub]);
        const int col = ct * 16 + rl;
        #pragma unroll
        for (int sub = 0; sub < 4; ++sub) {
          const int r0 = g4 * 64 + sub * 16 + q * 4;  // 4 rows, same node (20%4==0)
          if (r0 < 1620) {
            const int node = r0 / 20;
            float s = 0.f;
            #pragma unroll
            for (int j = 0; j < 4; ++j) s += fmaxf(acc[sub][j] + rb1c, 0.f);
            atomicAdd(&sm[OFF_MS + node * LDA + col], s);
          }
        }
      }
    }
    __syncthreads();

    // phase 3..6: M' -> g0 -> g1 -> x_in
    stage96(sm, OFF_MS, WS, W_REL2, 18, 6, rel_b2, 20.f, false, false, &sm[OFF_AP], LDA, wave, lane);
    __syncthreads();
    stage96(sm, OFF_AP, WS, W_G0B, 18, 6, nullptr, 0.f, true, true,  &sm[OFF_BV], LDA, wave, lane);
    __syncthreads();
    stage96(sm, OFF_BV, WS, W_G1, 18, 6, g_b1, 1.f, true,  false, &sm[OFF_AP], LDA, wave, lane);
    __syncthreads();
    stage96(sm, OFF_AP, WS, W_G2, 18, 6, g_b2, 1.f, false, false, &sm[OFF_BV], LDA, wave, lane);
    __syncthreads();

    // phase 7: LSTM gates = x_in@wih + h@whh + (bih+bhh); c in registers
    float h2r[5][4];
    #pragma unroll
    for (int ui = 0; ui < 5; ++ui) {
      const int u = wave + ui * 8;
      if (u < 36) {
        const int rt = u % 6, cc = u / 6;
        const int row = rt * 16 + rl;
        short8v ah[6], al[6];
        #pragma unroll
        for (int kt = 0; kt < 3; ++kt)
          splitFrag(&sm[OFF_BV + row * LDA + kt * 32 + q * 8], ah[kt], al[kt]);
        #pragma unroll
        for (int kt = 3; kt < 6; ++kt)
          splitFrag(&sm[OFF_H + row * LDA + (kt - 3) * 32 + q * 8], ah[kt], al[kt]);
        float4v ga[4] = {{0,0,0,0},{0,0,0,0},{0,0,0,0},{0,0,0,0}};
        #pragma unroll
        for (int gate = 0; gate < 4; ++gate) {
          const int ct = gate * 6 + cc;
          #pragma unroll
          for (int kt = 0; kt < 6; ++kt) {
            const int base = (kt < 3) ? W_IH : W_HH;
            const short* bp = WS + base + (ct * 3 + (kt % 3)) * 512 + lane * 8;
            const short8v bh = *reinterpret_cast<const short8v*>(bp);
            const short8v bl = *reinterpret_cast<const short8v*>(bp + 72 * 512);
            ga[gate] = mfma3(ah[kt], al[kt], bh, bl, ga[gate]);
          }
        }
        const int col = cc * 16 + rl;
        #pragma unroll
        for (int j = 0; j < 4; ++j) {
          const float gi = ga[0][j] + bih[col]       + bhh[col];
          const float gf = ga[1][j] + bih[96 + col]  + bhh[96 + col];
          const float gg = ga[2][j] + bih[192 + col] + bhh[192 + col];
          const float go = ga[3][j] + bih[288 + col] + bhh[288 + col];
          const float c2 = sigm(gf) * creg[ui][j] + sigm(gi) * tanh_(gg);
          creg[ui][j] = c2;
          h2r[ui][j] = sigm(go) * tanh_(c2);
        }
      }
    }
    __syncthreads();
    #pragma unroll
    for (int ui = 0; ui < 5; ++ui) {
      const int u = wave + ui * 8;
      if (u < 36) {
        const int rt = u % 6, cc = u / 6;
        #pragma unroll
        for (int j = 0; j < 4; ++j) {
          const int row = rt * 16 + q * 4 + j, col = cc * 16 + rl;
          if (row < NN) sm[OFF_H + row * LDA + col] = h2r[ui][j];
        }
      }
    }
    __syncthreads();

    // phase 8..10: readout
    stage96(sm, OFF_H,  WS, W_R0, 18, 6, r_b0, 1.f, true, false, &sm[OFF_AP], LDA, wave, lane);
    __syncthreads();
    stage96(sm, OFF_AP, WS, W_R1, 18, 6, r_b1, 1.f, true, false, &sm[OFF_BV], LDA, wave, lane);
    __syncthreads();
    if (wave < 3) {  // r2: 96->16 (9 real cols), 3 row-tile-pairs
      const int rtp = wave;
      short8v ah[2][3], al[2][3];
      #pragma unroll
      for (int sub = 0; sub < 2; ++sub) {
        const int row = rtp * 32 + sub * 16 + rl;
        #pragma unroll
        for (int kt = 0; kt < 3; ++kt)
          splitFrag(&sm[OFF_BV + row * LDA + kt * 32 + q * 8], ah[sub][kt], al[sub][kt]);
      }
      float4v a0 = {0,0,0,0}, a1 = {0,0,0,0};
      #pragma unroll
      for (int kt = 0; kt < 3; ++kt) {
        const short* bp = WS + W_R2 + kt * 512 + lane * 8;
        const short8v bh = *reinterpret_cast<const short8v*>(bp);
        const short8v bl = *reinterpret_cast<const short8v*>(bp + 3 * 512);
        a0 = mfma3(ah[0][kt], al[0][kt], bh, bl, a0);
        a1 = mfma3(ah[1][kt], al[1][kt], bh, bl, a1);
      }
      if (rl < NOUT) {
        float* op = out + ((size_t)it * BATCH + b) * NN * NOUT;
        #pragma unroll
        for (int sub = 0; sub < 2; ++sub)
          #pragma unroll
          for (int j = 0; j < 4; ++j) {
            const int row = rtp * 32 + sub * 16 + q * 4 + j;
            if (row < NN) op[row * NOUT + rl] = (sub ? a1[j] : a0[j]) + r_b2[rl];
          }
      }
    }
    __syncthreads();
  }
}

extern "C" void kernel_launch(void* const* d_in, const int* in_sizes, int n_in,
                              void* d_out, int out_size, void* d_ws, size_t ws_size,
                              hipStream_t stream) {
  (void)in_sizes; (void)n_in; (void)out_size; (void)ws_size;
  const int* grids = (const int*)d_in[0];
  const int* iters = (const int*)d_in[1];
  const float *emb = (const float*)d_in[2],
    *in_w0 = (const float*)d_in[3],  *in_b0 = (const float*)d_in[4],
    *in_b1 = (const float*)d_in[6],  *in_b2 = (const float*)d_in[8],
    *rel_w0 = (const float*)d_in[9],  *rel_b0 = (const float*)d_in[10],
    *rel_w1 = (const float*)d_in[11], *rel_b1 = (const float*)d_in[12],
    *rel_w2 = (const float*)d_in[13], *rel_b2 = (const float*)d_in[14],
    *g_w0 = (const float*)d_in[15], *g_b0 = (const float*)d_in[16],
    *g_w1 = (const float*)d_in[17], *g_b1 = (const float*)d_in[18],
    *g_w2 = (const float*)d_in[19], *g_b2 = (const float*)d_in[20],
    *wih = (const float*)d_in[21], *whh = (const float*)d_in[22],
    *bih = (const float*)d_in[23], *bhh = (const float*)d_in[24],
    *r_w0 = (const float*)d_in[25], *r_b0 = (const float*)d_in[26],
    *r_w1 = (const float*)d_in[27], *r_b1 = (const float*)d_in[28],
    *r_w2 = (const float*)d_in[29], *r_b2 = (const float*)d_in[30],
    *c0 = (const float*)d_in[31];
  short* ws = (short*)d_ws;
  pack_kernel<<<dim3(363), dim3(64), 0, stream>>>(
      rel_w0, rel_w1, rel_w2, g_w0, g_w1, g_w2, wih, whh,
      r_w0, r_w1, r_w2, (const float*)d_in[5], (const float*)d_in[7], ws);
  rrn_kernel<<<dim3(BATCH), dim3(BLOCK), 0, stream>>>(
      grids, iters, emb, in_w0, in_b0, in_b1, in_b2,
      rel_b0, rel_b1, rel_b2, g_b0, g_b1, g_b2,
      bih, bhh, r_b0, r_b1, r_b2, c0, (const short*)ws, (float*)d_out);
}

// Round 7
// 1982.619 us; speedup vs baseline: 1.1489x; 1.1489x over previous
//
#include <hip/hip_runtime.h>
#include <hip/hip_bf16.h>
#include <stdint.h>

typedef __attribute__((ext_vector_type(8))) short short8v;  // MFMA bf16 A/B frag (guide §3)
typedef __attribute__((ext_vector_type(4))) float float4v;  // MFMA C/D frag

#define DEVI __device__ __forceinline__

constexpr int BATCH = 256;
constexpr int NN   = 81;
constexpr int HID  = 96;
constexpr int NOUT = 9;
constexpr int BLOCK = 512;
constexpr int LDA = 100;   // LDS f32 row stride: mult of 4 (16B-aligned rows) + bank rotation

// LDS float offsets (frag-read buffers stride LDA; Xg stride 96). Pad-row frag reads
// (rows 81..95) spill into the NEXT region - harmless finite garbage, C rows masked on write.
constexpr int OFF_H  = 0;
constexpr int OFF_AP = 8100;    // 81*100
constexpr int OFF_BV = 16200;
constexpr int OFF_MS = 24300;
constexpr int OFF_XG = 32400;   // 81*96
constexpr int SMEM_F = 40176;   // 160,704 B <= 163,840

// packed weights in d_ws (shorts). Per matrix: hi tiles [(ct*3+kt)*512 + lane*8 + j],
// lo plane at +ntiles*512. ALL source matrices are [K rows][C cols] row-major.
// rel_w0 / g_w0 are 192x96 (K=192): packed as TWO 96x96 halves (rows 0..95 / 96..191).
constexpr int W_REL0A = 0;       // rel_w0 rows 0..95   (self proj)
constexpr int W_REL0B = 18432;   // rel_w0 rows 96..191 (neighbor proj)
constexpr int W_REL1  = 36864;
constexpr int W_REL2  = 55296;
constexpr int W_G0B   = 73728;   // g_w0 rows 96..191
constexpr int W_G1    = 92160;
constexpr int W_G2    = 110592;
constexpr int W_IH    = 129024;  // 96x384, 72 tiles
constexpr int W_HH    = 202752;
constexpr int W_R0    = 276480;
constexpr int W_R1    = 294912;
constexpr int W_R2    = 313344;  // 96x16 (cols 9..15 zero), 3 tiles
constexpr int W_IN1   = 316416;
constexpr int W_IN2   = 334848;
constexpr int W_G0A   = 353280;  // g_w0 rows 0..95 ; end 371,712 shorts = 743,424 B

DEVI float sigm(float x)  { return 1.f / (1.f + __expf(-x)); }
DEVI float tanh_(float x) { return 1.f - 2.f / (__expf(2.f * x) + 1.f); }

// hi = truncate-to-bf16 (exact residual in f32), lo = RNE-bf16(x - hi): rel err ~2^-15
DEVI short bfhi(float x) { union { float f; unsigned u; } v; v.f = x; return (short)(v.u >> 16); }
DEVI float fromBits(short s) { union { unsigned u; float f; } v; v.u = ((unsigned)(unsigned short)s) << 16; return v.f; }
DEVI short bfrne(float x) {
  union { float f; unsigned u; } v; v.f = x;
  unsigned r = v.u + 0x7fffu + ((v.u >> 16) & 1u);
  return (short)(r >> 16);
}
DEVI void split1(float x, short& h, short& l) { h = bfhi(x); l = bfrne(x - fromBits(h)); }

DEVI void splitFrag(const float* p, short8v& hv, short8v& lv) {
  const float4 a = *reinterpret_cast<const float4*>(p);
  const float4 b = *reinterpret_cast<const float4*>(p + 4);
  short h, l;
  split1(a.x, h, l); hv[0] = h; lv[0] = l;
  split1(a.y, h, l); hv[1] = h; lv[1] = l;
  split1(a.z, h, l); hv[2] = h; lv[2] = l;
  split1(a.w, h, l); hv[3] = h; lv[3] = l;
  split1(b.x, h, l); hv[4] = h; lv[4] = l;
  split1(b.y, h, l); hv[5] = h; lv[5] = l;
  split1(b.z, h, l); hv[6] = h; lv[6] = l;
  split1(b.w, h, l); hv[7] = h; lv[7] = l;
}
// t0 = relu(Ap_row + Bv_row), split
DEVI void splitFragPair(const float* ap, const float* bp, short8v& hv, short8v& lv) {
  const float4 a0 = *reinterpret_cast<const float4*>(ap);
  const float4 a1 = *reinterpret_cast<const float4*>(ap + 4);
  const float4 b0 = *reinterpret_cast<const float4*>(bp);
  const float4 b1 = *reinterpret_cast<const float4*>(bp + 4);
  float v[8] = { a0.x + b0.x, a0.y + b0.y, a0.z + b0.z, a0.w + b0.w,
                 a1.x + b1.x, a1.y + b1.y, a1.z + b1.z, a1.w + b1.w };
  short h, l;
  #pragma unroll
  for (int i = 0; i < 8; ++i) { split1(fmaxf(v[i], 0.f), h, l); hv[i] = h; lv[i] = l; }
}

DEVI float4v mfma3(short8v ah, short8v al, short8v bh, short8v bl, float4v acc) {
  acc = __builtin_amdgcn_mfma_f32_16x16x32_bf16(ah, bh, acc, 0, 0, 0);
  acc = __builtin_amdgcn_mfma_f32_16x16x32_bf16(al, bh, acc, 0, 0, 0);
  acc = __builtin_amdgcn_mfma_f32_16x16x32_bf16(ah, bl, acc, 0, 0, 0);
  return acc;
}

// e-th Sudoku peer of node n (order-free: message sum is permutation-invariant)
DEVI int nbr_of(int n, int e) {
  const int r = n / 9, c = n - 9 * r;
  if (e < 8)  { int cc = c + 1 + e;  if (cc >= 9) cc -= 9; return r * 9 + cc; }
  if (e < 16) { int rr = r + e - 7;  if (rr >= 9) rr -= 9; return rr * 9 + c; }
  const int q = e - 16, dr = 1 + (q >> 1), dc = 1 + (q & 1);
  const int rm = r % 3, cm = c % 3;
  int rr = r - rm + rm + dr; rr -= (rm + dr >= 3) ? 3 : 0;
  int cc = c - cm + cm + dc; cc -= (cm + dc >= 3) ? 3 : 0;
  return rr * 9 + cc;
}

// ---------------- weight pack kernel ----------------
__global__ __launch_bounds__(64)
void pack_kernel(const float* rel_w0, const float* rel_w1, const float* rel_w2,
                 const float* g_w0, const float* g_w1, const float* g_w2,
                 const float* wih, const float* whh,
                 const float* r_w0, const float* r_w1, const float* r_w2,
                 const float* in_w1, const float* in_w2, short* ws)
{
  const int lane = threadIdx.x;
  const int blk = blockIdx.x;
  const int starts[16] = {0,18,36,54,72,90,108,126,198,270,288,306,309,327,345,363};
  int mi = 0;
  while (blk >= starts[mi + 1]) ++mi;
  const int tt = blk - starts[mi];
  const int ntile = starts[mi + 1] - starts[mi];
  const float* src; int C = 96, row0 = 0, off;
  switch (mi) {
    case 0:  src = rel_w0; off = W_REL0A; break;            // rel_w0[0:96]   (192x96!)
    case 1:  src = rel_w0; row0 = 96; off = W_REL0B; break; // rel_w0[96:192]
    case 2:  src = rel_w1; off = W_REL1; break;
    case 3:  src = rel_w2; off = W_REL2; break;
    case 4:  src = g_w0; row0 = 96; off = W_G0B; break;
    case 5:  src = g_w1; off = W_G1; break;
    case 6:  src = g_w2; off = W_G2; break;
    case 7:  src = wih; C = 384; off = W_IH; break;
    case 8:  src = whh; C = 384; off = W_HH; break;
    case 9:  src = r_w0; off = W_R0; break;
    case 10: src = r_w1; off = W_R1; break;
    case 11: src = r_w2; C = 9; off = W_R2; break;
    case 12: src = in_w1; off = W_IN1; break;
    case 13: src = in_w2; off = W_IN2; break;
    default: src = g_w0; off = W_G0A; break;
  }
  const int kt = tt % 3, ct = tt / 3;
  const int q = lane >> 4, r = lane & 15;
  const int c = ct * 16 + r;
  short* hd = ws + off + tt * 512 + lane * 8;
  short* ld = hd + ntile * 512;
  #pragma unroll
  for (int j = 0; j < 8; ++j) {
    const int k = row0 + kt * 32 + q * 8 + j;
    float w = (c < C) ? src[k * C + c] : 0.f;
    short h, l; split1(w, h, l);
    hd[j] = h; ld[j] = l;
  }
}

// ---------------- generic node-GEMM stage: dst[81 x (CT*16)] = act(A[81x96] @ W + ...) ----------------
DEVI void stage96(float* sm, int aOff, const short* WS, int wOff, int wTiles, int CT,
                  const float* bias, float bscale, bool relu, bool xgAdd,
                  float* dst, int dstLD, int wave, int lane)
{
  const int rl = lane & 15, q = lane >> 4;
  const int plane = wTiles * 512;
  #pragma unroll 1
  for (int t = wave; t < 3 * CT; t += 8) {
    const int rtp = t % 3, ct = t / 3;
    short8v ah[2][3], al[2][3];
    #pragma unroll
    for (int sub = 0; sub < 2; ++sub) {
      const int row = rtp * 32 + sub * 16 + rl;
      const float* ap = &sm[aOff + row * LDA + q * 8];
      #pragma unroll
      for (int kt = 0; kt < 3; ++kt) splitFrag(ap + kt * 32, ah[sub][kt], al[sub][kt]);
    }
    float4v acc0 = {0.f, 0.f, 0.f, 0.f}, acc1 = {0.f, 0.f, 0.f, 0.f};
    #pragma unroll
    for (int kt = 0; kt < 3; ++kt) {
      const short* bp = WS + wOff + (ct * 3 + kt) * 512 + lane * 8;
      const short8v bh = *reinterpret_cast<const short8v*>(bp);
      const short8v bl = *reinterpret_cast<const short8v*>(bp + plane);
      acc0 = mfma3(ah[0][kt], al[0][kt], bh, bl, acc0);
      acc1 = mfma3(ah[1][kt], al[1][kt], bh, bl, acc1);
    }
    const int col = ct * 16 + rl;
    #pragma unroll
    for (int sub = 0; sub < 2; ++sub) {
      #pragma unroll
      for (int j = 0; j < 4; ++j) {
        const int row = rtp * 32 + sub * 16 + q * 4 + j;
        if (row < NN) {
          float v = sub ? acc1[j] : acc0[j];
          if (bias)  v += bias[col] * bscale;
          if (xgAdd) v += sm[OFF_XG + row * 96 + col];
          if (relu)  v = fmaxf(v, 0.f);
          dst[row * dstLD + col] = v;
        }
      }
    }
  }
}

// ---------------- main kernel ----------------
// waves_per_eu(1,2): occupancy is LDS-capped at 1 block (8 waves = 2/EU) anyway,
// so don't let the allocator target 4 waves/EU (=128 VGPR cap -> r5/r6's 650MB spill).
__global__ __launch_bounds__(BLOCK) __attribute__((amdgpu_waves_per_eu(1, 2)))
void rrn_kernel(const int* __restrict__ grids, const int* __restrict__ itersp,
                const float* __restrict__ emb, const float* __restrict__ in_w0,
                const float* __restrict__ in_b0, const float* __restrict__ in_b1,
                const float* __restrict__ in_b2,
                const float* __restrict__ rel_b0, const float* __restrict__ rel_b1,
                const float* __restrict__ rel_b2,
                const float* __restrict__ g_b0, const float* __restrict__ g_b1,
                const float* __restrict__ g_b2,
                const float* __restrict__ bih, const float* __restrict__ bhh,
                const float* __restrict__ r_b0, const float* __restrict__ r_b1,
                const float* __restrict__ r_b2,
                const float* __restrict__ c0, const short* __restrict__ WS,
                float* __restrict__ out)
{
  __shared__ float sm[SMEM_F];
  const int b = blockIdx.x, tid = threadIdx.x;
  const int wave = tid >> 6, lane = tid & 63;
  const int rl = lane & 15, q = lane >> 4;
  const int iters = itersp[0];

  // LSTM cell state in registers: unit u = wave + ui*8 (u<36): rt=u%6, cc=u/6
  float creg[5][4];
  #pragma unroll
  for (int ui = 0; ui < 5; ++ui) {
    const int u = wave + ui * 8;
    if (u < 36) {
      const int rt = u % 6, cc = u / 6;
      #pragma unroll
      for (int j = 0; j < 4; ++j) {
        const int row = rt * 16 + q * 4 + j, col = cc * 16 + rl;
        creg[ui][j] = (row < NN) ? c0[(size_t)b * NN * HID + row * HID + col] : 0.f;
      }
    }
  }

  // ---- prologue: embed L0 (VALU, K=16) then MFMA stages ----
  for (int t = tid; t < NN * HID; t += BLOCK) {
    const int n = t / HID, col = t - n * HID;
    const int g = grids[b * NN + n];
    float acc = in_b0[col];
    #pragma unroll
    for (int k = 0; k < 16; ++k) acc += emb[g * 16 + k] * in_w0[k * HID + col];
    sm[OFF_AP + n * LDA + col] = fmaxf(acc, 0.f);
  }
  __syncthreads();
  stage96(sm, OFF_AP, WS, W_IN1, 18, 6, in_b1, 1.f, true,  false, &sm[OFF_BV], LDA, wave, lane);
  __syncthreads();
  stage96(sm, OFF_BV, WS, W_IN2, 18, 6, in_b2, 1.f, false, false, &sm[OFF_H],  LDA, wave, lane);
  __syncthreads();
  stage96(sm, OFF_H,  WS, W_G0A, 18, 6, g_b0,  1.f, false, false, &sm[OFF_XG], 96,  wave, lane);
  __syncthreads();

  for (int it = 0; it < iters; ++it) {
    // phase 1: zero Msum; Ap = h@rel_w0[0:96] + rel_b0 ; Bv = h@rel_w0[96:192]
    for (int i = tid; i < 8100; i += BLOCK) sm[OFF_MS + i] = 0.f;
    stage96(sm, OFF_H, WS, W_REL0A, 18, 6, rel_b0, 1.f, false, false, &sm[OFF_AP], LDA, wave, lane);
    stage96(sm, OFF_H, WS, W_REL0B, 18, 6, nullptr, 0.f, false, false, &sm[OFF_BV], LDA, wave, lane);
    __syncthreads();

    // phase 2: pair GEMM, 51 wave-private groups of 32 pair-rows (2-sub: ~115 live VGPR,
    // no spill at a 128 cap; ct loop pinned unroll-1 so B-frags don't multiply pressure)
    #pragma unroll 1
    for (int g2 = wave; g2 < 51; g2 += 8) {
      short8v ah[2][3], al[2][3];
      #pragma unroll
      for (int sub = 0; sub < 2; ++sub) {
        const int row = g2 * 32 + sub * 16 + rl;
        if (row < 1620) {
          const int n = row / 20, e = row - 20 * n, m = nbr_of(n, e);
          const float* ap = &sm[OFF_AP + n * LDA + q * 8];
          const float* bp = &sm[OFF_BV + m * LDA + q * 8];
          #pragma unroll
          for (int kt = 0; kt < 3; ++kt)
            splitFragPair(ap + kt * 32, bp + kt * 32, ah[sub][kt], al[sub][kt]);
        } else {
          const short8v z = {0,0,0,0,0,0,0,0};
          #pragma unroll
          for (int kt = 0; kt < 3; ++kt) { ah[sub][kt] = z; al[sub][kt] = z; }
        }
      }
      #pragma unroll 1
      for (int ct = 0; ct < 6; ++ct) {
        const float rb1c = rel_b1[ct * 16 + rl];   // L1-resident
        float4v acc0 = {0,0,0,0}, acc1 = {0,0,0,0};
        #pragma unroll
        for (int kt = 0; kt < 3; ++kt) {
          const short* bp = WS + W_REL1 + (ct * 3 + kt) * 512 + lane * 8;
          const short8v bh = *reinterpret_cast<const short8v*>(bp);
          const short8v bl = *reinterpret_cast<const short8v*>(bp + 18 * 512);
          acc0 = mfma3(ah[0][kt], al[0][kt], bh, bl, acc0);
          acc1 = mfma3(ah[1][kt], al[1][kt], bh, bl, acc1);
        }
        const int col = ct * 16 + rl;
        #pragma unroll
        for (int sub = 0; sub < 2; ++sub) {
          const int r0 = g2 * 32 + sub * 16 + q * 4;  // 4 rows, same node (20%4==0)
          if (r0 < 1620) {
            const int node = r0 / 20;
            const float4v a = sub ? acc1 : acc0;
            const float s = fmaxf(a[0] + rb1c, 0.f) + fmaxf(a[1] + rb1c, 0.f)
                          + fmaxf(a[2] + rb1c, 0.f) + fmaxf(a[3] + rb1c, 0.f);
            atomicAdd(&sm[OFF_MS + node * LDA + col], s);
          }
        }
      }
    }
    __syncthreads();

    // phase 3..6: M' -> g0 -> g1 -> x_in
    stage96(sm, OFF_MS, WS, W_REL2, 18, 6, rel_b2, 20.f, false, false, &sm[OFF_AP], LDA, wave, lane);
    __syncthreads();
    stage96(sm, OFF_AP, WS, W_G0B, 18, 6, nullptr, 0.f, true, true,  &sm[OFF_BV], LDA, wave, lane);
    __syncthreads();
    stage96(sm, OFF_BV, WS, W_G1, 18, 6, g_b1, 1.f, true,  false, &sm[OFF_AP], LDA, wave, lane);
    __syncthreads();
    stage96(sm, OFF_AP, WS, W_G2, 18, 6, g_b2, 1.f, false, false, &sm[OFF_BV], LDA, wave, lane);
    __syncthreads();

    // phase 7: LSTM gates = x_in@wih + h@whh + (bih+bhh); c in registers
    float h2r[5][4];
    #pragma unroll
    for (int ui = 0; ui < 5; ++ui) {
      const int u = wave + ui * 8;
      if (u < 36) {
        const int rt = u % 6, cc = u / 6;
        const int row = rt * 16 + rl;
        short8v ah[6], al[6];
        #pragma unroll
        for (int kt = 0; kt < 3; ++kt)
          splitFrag(&sm[OFF_BV + row * LDA + kt * 32 + q * 8], ah[kt], al[kt]);
        #pragma unroll
        for (int kt = 3; kt < 6; ++kt)
          splitFrag(&sm[OFF_H + row * LDA + (kt - 3) * 32 + q * 8], ah[kt], al[kt]);
        float4v ga[4] = {{0,0,0,0},{0,0,0,0},{0,0,0,0},{0,0,0,0}};
        #pragma unroll
        for (int gate = 0; gate < 4; ++gate) {
          const int ct = gate * 6 + cc;
          #pragma unroll
          for (int kt = 0; kt < 6; ++kt) {
            const int base = (kt < 3) ? W_IH : W_HH;
            const short* bp = WS + base + (ct * 3 + (kt % 3)) * 512 + lane * 8;
            const short8v bh = *reinterpret_cast<const short8v*>(bp);
            const short8v bl = *reinterpret_cast<const short8v*>(bp + 72 * 512);
            ga[gate] = mfma3(ah[kt], al[kt], bh, bl, ga[gate]);
          }
        }
        const int col = cc * 16 + rl;
        #pragma unroll
        for (int j = 0; j < 4; ++j) {
          const float gi = ga[0][j] + bih[col]       + bhh[col];
          const float gf = ga[1][j] + bih[96 + col]  + bhh[96 + col];
          const float gg = ga[2][j] + bih[192 + col] + bhh[192 + col];
          const float go = ga[3][j] + bih[288 + col] + bhh[288 + col];
          const float c2 = sigm(gf) * creg[ui][j] + sigm(gi) * tanh_(gg);
          creg[ui][j] = c2;
          h2r[ui][j] = sigm(go) * tanh_(c2);
        }
      }
    }
    __syncthreads();
    #pragma unroll
    for (int ui = 0; ui < 5; ++ui) {
      const int u = wave + ui * 8;
      if (u < 36) {
        const int rt = u % 6, cc = u / 6;
        #pragma unroll
        for (int j = 0; j < 4; ++j) {
          const int row = rt * 16 + q * 4 + j, col = cc * 16 + rl;
          if (row < NN) sm[OFF_H + row * LDA + col] = h2r[ui][j];
        }
      }
    }
    __syncthreads();

    // phase 8..10: readout
    stage96(sm, OFF_H,  WS, W_R0, 18, 6, r_b0, 1.f, true, false, &sm[OFF_AP], LDA, wave, lane);
    __syncthreads();
    stage96(sm, OFF_AP, WS, W_R1, 18, 6, r_b1, 1.f, true, false, &sm[OFF_BV], LDA, wave, lane);
    __syncthreads();
    if (wave < 3) {  // r2: 96->16 (9 real cols), 3 row-tile-pairs
      const int rtp = wave;
      short8v ah[2][3], al[2][3];
      #pragma unroll
      for (int sub = 0; sub < 2; ++sub) {
        const int row = rtp * 32 + sub * 16 + rl;
        #pragma unroll
        for (int kt = 0; kt < 3; ++kt)
          splitFrag(&sm[OFF_BV + row * LDA + kt * 32 + q * 8], ah[sub][kt], al[sub][kt]);
      }
      float4v a0 = {0,0,0,0}, a1 = {0,0,0,0};
      #pragma unroll
      for (int kt = 0; kt < 3; ++kt) {
        const short* bp = WS + W_R2 + kt * 512 + lane * 8;
        const short8v bh = *reinterpret_cast<const short8v*>(bp);
        const short8v bl = *reinterpret_cast<const short8v*>(bp + 3 * 512);
        a0 = mfma3(ah[0][kt], al[0][kt], bh, bl, a0);
        a1 = mfma3(ah[1][kt], al[1][kt], bh, bl, a1);
      }
      if (rl < NOUT) {
        float* op = out + ((size_t)it * BATCH + b) * NN * NOUT;
        #pragma unroll
        for (int sub = 0; sub < 2; ++sub)
          #pragma unroll
          for (int j = 0; j < 4; ++j) {
            const int row = rtp * 32 + sub * 16 + q * 4 + j;
            if (row < NN) op[row * NOUT + rl] = (sub ? a1[j] : a0[j]) + r_b2[rl];
          }
      }
    }
    __syncthreads();
  }
}

extern "C" void kernel_launch(void* const* d_in, const int* in_sizes, int n_in,
                              void* d_out, int out_size, void* d_ws, size_t ws_size,
                              hipStream_t stream) {
  (void)in_sizes; (void)n_in; (void)out_size; (void)ws_size;
  const int* grids = (const int*)d_in[0];
  const int* iters = (const int*)d_in[1];
  const float *emb = (const float*)d_in[2],
    *in_w0 = (const float*)d_in[3],  *in_b0 = (const float*)d_in[4],
    *in_b1 = (const float*)d_in[6],  *in_b2 = (const float*)d_in[8],
    *rel_w0 = (const float*)d_in[9],  *rel_b0 = (const float*)d_in[10],
    *rel_w1 = (const float*)d_in[11], *rel_b1 = (const float*)d_in[12],
    *rel_w2 = (const float*)d_in[13], *rel_b2 = (const float*)d_in[14],
    *g_w0 = (const float*)d_in[15], *g_b0 = (const float*)d_in[16],
    *g_w1 = (const float*)d_in[17], *g_b1 = (const float*)d_in[18],
    *g_w2 = (const float*)d_in[19], *g_b2 = (const float*)d_in[20],
    *wih = (const float*)d_in[21], *whh = (const float*)d_in[22],
    *bih = (const float*)d_in[23], *bhh = (const float*)d_in[24],
    *r_w0 = (const float*)d_in[25], *r_b0 = (const float*)d_in[26],
    *r_w1 = (const float*)d_in[27], *r_b1 = (const float*)d_in[28],
    *r_w2 = (const float*)d_in[29], *r_b2 = (const float*)d_in[30],
    *c0 = (const float*)d_in[31];
  short* ws = (short*)d_ws;
  pack_kernel<<<dim3(363), dim3(64), 0, stream>>>(
      rel_w0, rel_w1, rel_w2, g_w0, g_w1, g_w2, wih, whh,
      r_w0, r_w1, r_w2, (const float*)d_in[5], (const float*)d_in[7], ws);
  rrn_kernel<<<dim3(BATCH), dim3(BLOCK), 0, stream>>>(
      grids, iters, emb, in_w0, in_b0, in_b1, in_b2,
      rel_b0, rel_b1, rel_b2, g_b0, g_b1, g_b2,
      bih, bhh, r_b0, r_b1, r_b2, c0, (const short*)ws, (float*)d_out);
}

// Round 8
// 1924.449 us; speedup vs baseline: 1.1836x; 1.0302x over previous
//
#include <hip/hip_runtime.h>
#include <hip/hip_bf16.h>
#include <stdint.h>

typedef __attribute__((ext_vector_type(8))) short short8v;  // MFMA bf16 A/B frag (guide §3)
typedef __attribute__((ext_vector_type(4))) float float4v;  // MFMA C/D frag

#define DEVI __device__ __forceinline__

constexpr int BATCH = 256;
constexpr int NN   = 81;
constexpr int HID  = 96;
constexpr int NOUT = 9;
constexpr int BLOCK = 512;
constexpr int LDA = 100;   // LDS f32 row stride: mult of 4 (16B-aligned rows) + bank rotation

// LDS float offsets (frag-read buffers stride LDA; Xg stride 96). Pad-row frag reads
// (rows 81..95) spill into the NEXT region - harmless finite garbage, C rows masked on write.
constexpr int OFF_H  = 0;
constexpr int OFF_AP = 8100;    // 81*100
constexpr int OFF_BV = 16200;
constexpr int OFF_MS = 24300;
constexpr int OFF_XG = 32400;   // 81*96
constexpr int SMEM_F = 40176;   // 160,704 B <= 163,840

// packed weights in d_ws (shorts). Per matrix: hi tiles [(ct*3+kt)*512 + lane*8 + j],
// lo plane at +ntiles*512. ALL source matrices are [K rows][C cols] row-major.
// rel_w0 / g_w0 are 192x96 (K=192): packed as TWO 96x96 halves (rows 0..95 / 96..191).
constexpr int W_REL0A = 0;       // rel_w0 rows 0..95   (self proj)
constexpr int W_REL0B = 18432;   // rel_w0 rows 96..191 (neighbor proj)
constexpr int W_REL1  = 36864;
constexpr int W_REL2  = 55296;
constexpr int W_G0B   = 73728;   // g_w0 rows 96..191
constexpr int W_G1    = 92160;
constexpr int W_G2    = 110592;
constexpr int W_IH    = 129024;  // 96x384, 72 tiles
constexpr int W_HH    = 202752;
constexpr int W_R0    = 276480;
constexpr int W_R1    = 294912;
constexpr int W_R2    = 313344;  // 96x16 (cols 9..15 zero), 3 tiles
constexpr int W_IN1   = 316416;
constexpr int W_IN2   = 334848;
constexpr int W_G0A   = 353280;  // g_w0 rows 0..95 ; end 371,712 shorts = 743,424 B

DEVI float sigm(float x)  { return 1.f / (1.f + __expf(-x)); }
DEVI float tanh_(float x) { return 1.f - 2.f / (__expf(2.f * x) + 1.f); }

// weight split: hi = truncate-to-bf16, lo = RNE-bf16(x - hi): combined rel err ~2^-16
DEVI short bfhi(float x) { union { float f; unsigned u; } v; v.f = x; return (short)(v.u >> 16); }
DEVI float fromBits(short s) { union { unsigned u; float f; } v; v.u = ((unsigned)(unsigned short)s) << 16; return v.f; }
DEVI short bfrne(float x) {
  union { float f; unsigned u; } v; v.f = x;
  unsigned r = v.u + 0x7fffu + ((v.u >> 16) & 1u);
  return (short)(r >> 16);
}
DEVI void split1(float x, short& h, short& l) { h = bfhi(x); l = bfrne(x - fromBits(h)); }

// A-side: SINGLE RNE bf16 (v3-verified precision regime; halves frag registers + 1/3 of MFMAs)
DEVI void packFrag(const float* p, short8v& v) {
  const float4 a = *reinterpret_cast<const float4*>(p);
  const float4 b = *reinterpret_cast<const float4*>(p + 4);
  v[0] = bfrne(a.x); v[1] = bfrne(a.y); v[2] = bfrne(a.z); v[3] = bfrne(a.w);
  v[4] = bfrne(b.x); v[5] = bfrne(b.y); v[6] = bfrne(b.z); v[7] = bfrne(b.w);
}
// t0 = relu(Ap_row + Bv_row), RNE-packed
DEVI void packFragPair(const float* ap, const float* bp, short8v& v) {
  const float4 a0 = *reinterpret_cast<const float4*>(ap);
  const float4 a1 = *reinterpret_cast<const float4*>(ap + 4);
  const float4 b0 = *reinterpret_cast<const float4*>(bp);
  const float4 b1 = *reinterpret_cast<const float4*>(bp + 4);
  v[0] = bfrne(fmaxf(a0.x + b0.x, 0.f)); v[1] = bfrne(fmaxf(a0.y + b0.y, 0.f));
  v[2] = bfrne(fmaxf(a0.z + b0.z, 0.f)); v[3] = bfrne(fmaxf(a0.w + b0.w, 0.f));
  v[4] = bfrne(fmaxf(a1.x + b1.x, 0.f)); v[5] = bfrne(fmaxf(a1.y + b1.y, 0.f));
  v[6] = bfrne(fmaxf(a1.z + b1.z, 0.f)); v[7] = bfrne(fmaxf(a1.w + b1.w, 0.f));
}

// acc += A * (Wh + Wl): 2 MFMAs, weight error ~2^-16, activation error ~2^-9 (dominates, = v3)
DEVI float4v mfma2(short8v a, short8v bh, short8v bl, float4v acc) {
  acc = __builtin_amdgcn_mfma_f32_16x16x32_bf16(a, bh, acc, 0, 0, 0);
  acc = __builtin_amdgcn_mfma_f32_16x16x32_bf16(a, bl, acc, 0, 0, 0);
  return acc;
}

// e-th Sudoku peer of node n (order-free: message sum is permutation-invariant)
DEVI int nbr_of(int n, int e) {
  const int r = n / 9, c = n - 9 * r;
  if (e < 8)  { int cc = c + 1 + e;  if (cc >= 9) cc -= 9; return r * 9 + cc; }
  if (e < 16) { int rr = r + e - 7;  if (rr >= 9) rr -= 9; return rr * 9 + c; }
  const int q = e - 16, dr = 1 + (q >> 1), dc = 1 + (q & 1);
  const int rm = r % 3, cm = c % 3;
  int rr = r - rm + rm + dr; rr -= (rm + dr >= 3) ? 3 : 0;
  int cc = c - cm + cm + dc; cc -= (cm + dc >= 3) ? 3 : 0;
  return rr * 9 + cc;
}

// ---------------- weight pack kernel ----------------
__global__ __launch_bounds__(64)
void pack_kernel(const float* rel_w0, const float* rel_w1, const float* rel_w2,
                 const float* g_w0, const float* g_w1, const float* g_w2,
                 const float* wih, const float* whh,
                 const float* r_w0, const float* r_w1, const float* r_w2,
                 const float* in_w1, const float* in_w2, short* ws)
{
  const int lane = threadIdx.x;
  const int blk = blockIdx.x;
  const int starts[16] = {0,18,36,54,72,90,108,126,198,270,288,306,309,327,345,363};
  int mi = 0;
  while (blk >= starts[mi + 1]) ++mi;
  const int tt = blk - starts[mi];
  const int ntile = starts[mi + 1] - starts[mi];
  const float* src; int C = 96, row0 = 0, off;
  switch (mi) {
    case 0:  src = rel_w0; off = W_REL0A; break;            // rel_w0[0:96]   (192x96!)
    case 1:  src = rel_w0; row0 = 96; off = W_REL0B; break; // rel_w0[96:192]
    case 2:  src = rel_w1; off = W_REL1; break;
    case 3:  src = rel_w2; off = W_REL2; break;
    case 4:  src = g_w0; row0 = 96; off = W_G0B; break;
    case 5:  src = g_w1; off = W_G1; break;
    case 6:  src = g_w2; off = W_G2; break;
    case 7:  src = wih; C = 384; off = W_IH; break;
    case 8:  src = whh; C = 384; off = W_HH; break;
    case 9:  src = r_w0; off = W_R0; break;
    case 10: src = r_w1; off = W_R1; break;
    case 11: src = r_w2; C = 9; off = W_R2; break;
    case 12: src = in_w1; off = W_IN1; break;
    case 13: src = in_w2; off = W_IN2; break;
    default: src = g_w0; off = W_G0A; break;
  }
  const int kt = tt % 3, ct = tt / 3;
  const int q = lane >> 4, r = lane & 15;
  const int c = ct * 16 + r;
  short* hd = ws + off + tt * 512 + lane * 8;
  short* ld = hd + ntile * 512;
  #pragma unroll
  for (int j = 0; j < 8; ++j) {
    const int k = row0 + kt * 32 + q * 8 + j;
    float w = (c < C) ? src[k * C + c] : 0.f;
    short h, l; split1(w, h, l);
    hd[j] = h; ld[j] = l;
  }
}

// ---------------- generic node-GEMM stage: dst[81 x (CT*16)] = act(A[81x96] @ W + ...) ----------------
DEVI void stage96(float* sm, int aOff, const short* WS, int wOff, int wTiles, int CT,
                  const float* bias, float bscale, bool relu, bool xgAdd,
                  float* dst, int dstLD, int wave, int lane)
{
  const int rl = lane & 15, q = lane >> 4;
  const int plane = wTiles * 512;
  #pragma unroll 1
  for (int t = wave; t < 3 * CT; t += 8) {
    const int rtp = t % 3, ct = t / 3;
    short8v a2[2][3];
    #pragma unroll
    for (int sub = 0; sub < 2; ++sub) {
      const int row = rtp * 32 + sub * 16 + rl;
      const float* ap = &sm[aOff + row * LDA + q * 8];
      #pragma unroll
      for (int kt = 0; kt < 3; ++kt) packFrag(ap + kt * 32, a2[sub][kt]);
    }
    float4v acc0 = {0.f, 0.f, 0.f, 0.f}, acc1 = {0.f, 0.f, 0.f, 0.f};
    #pragma unroll
    for (int kt = 0; kt < 3; ++kt) {
      const short* bp = WS + wOff + (ct * 3 + kt) * 512 + lane * 8;
      const short8v bh = *reinterpret_cast<const short8v*>(bp);
      const short8v bl = *reinterpret_cast<const short8v*>(bp + plane);
      acc0 = mfma2(a2[0][kt], bh, bl, acc0);
      acc1 = mfma2(a2[1][kt], bh, bl, acc1);
    }
    const int col = ct * 16 + rl;
    #pragma unroll
    for (int sub = 0; sub < 2; ++sub) {
      #pragma unroll
      for (int j = 0; j < 4; ++j) {
        const int row = rtp * 32 + sub * 16 + q * 4 + j;
        if (row < NN) {
          float v = sub ? acc1[j] : acc0[j];
          if (bias)  v += bias[col] * bscale;
          if (xgAdd) v += sm[OFF_XG + row * 96 + col];
          if (relu)  v = fmaxf(v, 0.f);
          dst[row * dstLD + col] = v;
        }
      }
    }
  }
}

// ---------------- main kernel ----------------
__global__ __launch_bounds__(BLOCK) __attribute__((amdgpu_waves_per_eu(1, 2)))
void rrn_kernel(const int* __restrict__ grids, const int* __restrict__ itersp,
                const float* __restrict__ emb, const float* __restrict__ in_w0,
                const float* __restrict__ in_b0, const float* __restrict__ in_b1,
                const float* __restrict__ in_b2,
                const float* __restrict__ rel_b0, const float* __restrict__ rel_b1,
                const float* __restrict__ rel_b2,
                const float* __restrict__ g_b0, const float* __restrict__ g_b1,
                const float* __restrict__ g_b2,
                const float* __restrict__ bih, const float* __restrict__ bhh,
                const float* __restrict__ r_b0, const float* __restrict__ r_b1,
                const float* __restrict__ r_b2,
                const float* __restrict__ c0, const short* __restrict__ WS,
                float* __restrict__ out)
{
  __shared__ float sm[SMEM_F];
  const int b = blockIdx.x, tid = threadIdx.x;
  const int wave = tid >> 6, lane = tid & 63;
  const int rl = lane & 15, q = lane >> 4;
  const int iters = itersp[0];

  // LSTM cell state in registers: unit u = wave + ui*8 (u<36): rt=u%6, cc=u/6
  float creg[5][4];
  #pragma unroll
  for (int ui = 0; ui < 5; ++ui) {
    const int u = wave + ui * 8;
    if (u < 36) {
      const int rt = u % 6, cc = u / 6;
      #pragma unroll
      for (int j = 0; j < 4; ++j) {
        const int row = rt * 16 + q * 4 + j, col = cc * 16 + rl;
        creg[ui][j] = (row < NN) ? c0[(size_t)b * NN * HID + row * HID + col] : 0.f;
      }
    }
  }

  // ---- prologue: embed L0 (VALU, K=16) then MFMA stages ----
  for (int t = tid; t < NN * HID; t += BLOCK) {
    const int n = t / HID, col = t - n * HID;
    const int g = grids[b * NN + n];
    float acc = in_b0[col];
    #pragma unroll
    for (int k = 0; k < 16; ++k) acc += emb[g * 16 + k] * in_w0[k * HID + col];
    sm[OFF_AP + n * LDA + col] = fmaxf(acc, 0.f);
  }
  __syncthreads();
  stage96(sm, OFF_AP, WS, W_IN1, 18, 6, in_b1, 1.f, true,  false, &sm[OFF_BV], LDA, wave, lane);
  __syncthreads();
  stage96(sm, OFF_BV, WS, W_IN2, 18, 6, in_b2, 1.f, false, false, &sm[OFF_H],  LDA, wave, lane);
  __syncthreads();
  stage96(sm, OFF_H,  WS, W_G0A, 18, 6, g_b0,  1.f, false, false, &sm[OFF_XG], 96,  wave, lane);
  __syncthreads();

  for (int it = 0; it < iters; ++it) {
    // phase 1: zero Msum; Ap = h@rel_w0[0:96] + rel_b0 ; Bv = h@rel_w0[96:192]
    for (int i = tid; i < 8100; i += BLOCK) sm[OFF_MS + i] = 0.f;
    stage96(sm, OFF_H, WS, W_REL0A, 18, 6, rel_b0, 1.f, false, false, &sm[OFF_AP], LDA, wave, lane);
    stage96(sm, OFF_H, WS, W_REL0B, 18, 6, nullptr, 0.f, false, false, &sm[OFF_BV], LDA, wave, lane);
    __syncthreads();

    // phase 2: pair GEMM, 51 wave-private groups of 32 pair-rows.
    // single-A live set ~67 VGPR: must not spill even at a 128-reg arch allocation.
    #pragma unroll 1
    for (int g2 = wave; g2 < 51; g2 += 8) {
      short8v a2[2][3];
      #pragma unroll
      for (int sub = 0; sub < 2; ++sub) {
        const int row = g2 * 32 + sub * 16 + rl;
        if (row < 1620) {
          const int n = row / 20, e = row - 20 * n, m = nbr_of(n, e);
          const float* ap = &sm[OFF_AP + n * LDA + q * 8];
          const float* bp = &sm[OFF_BV + m * LDA + q * 8];
          #pragma unroll
          for (int kt = 0; kt < 3; ++kt)
            packFragPair(ap + kt * 32, bp + kt * 32, a2[sub][kt]);
        } else {
          const short8v z = {0,0,0,0,0,0,0,0};
          #pragma unroll
          for (int kt = 0; kt < 3; ++kt) a2[sub][kt] = z;
        }
      }
      #pragma unroll 1
      for (int ct = 0; ct < 6; ++ct) {
        const float rb1c = rel_b1[ct * 16 + rl];   // L1-resident
        float4v acc0 = {0,0,0,0}, acc1 = {0,0,0,0};
        #pragma unroll
        for (int kt = 0; kt < 3; ++kt) {
          const short* bp = WS + W_REL1 + (ct * 3 + kt) * 512 + lane * 8;
          const short8v bh = *reinterpret_cast<const short8v*>(bp);
          const short8v bl = *reinterpret_cast<const short8v*>(bp + 18 * 512);
          acc0 = mfma2(a2[0][kt], bh, bl, acc0);
          acc1 = mfma2(a2[1][kt], bh, bl, acc1);
        }
        const int col = ct * 16 + rl;
        #pragma unroll
        for (int sub = 0; sub < 2; ++sub) {
          const int r0 = g2 * 32 + sub * 16 + q * 4;  // 4 rows, same node (20%4==0)
          if (r0 < 1620) {
            const int node = r0 / 20;
            const float4v a = sub ? acc1 : acc0;
            const float s = fmaxf(a[0] + rb1c, 0.f) + fmaxf(a[1] + rb1c, 0.f)
                          + fmaxf(a[2] + rb1c, 0.f) + fmaxf(a[3] + rb1c, 0.f);
            atomicAdd(&sm[OFF_MS + node * LDA + col], s);
          }
        }
      }
    }
    __syncthreads();

    // phase 3..6: M' -> g0 -> g1 -> x_in
    stage96(sm, OFF_MS, WS, W_REL2, 18, 6, rel_b2, 20.f, false, false, &sm[OFF_AP], LDA, wave, lane);
    __syncthreads();
    stage96(sm, OFF_AP, WS, W_G0B, 18, 6, nullptr, 0.f, true, true,  &sm[OFF_BV], LDA, wave, lane);
    __syncthreads();
    stage96(sm, OFF_BV, WS, W_G1, 18, 6, g_b1, 1.f, true,  false, &sm[OFF_AP], LDA, wave, lane);
    __syncthreads();
    stage96(sm, OFF_AP, WS, W_G2, 18, 6, g_b2, 1.f, false, false, &sm[OFF_BV], LDA, wave, lane);
    __syncthreads();

    // phase 7: LSTM gates = x_in@wih + h@whh + (bih+bhh); c in registers
    float h2r[5][4];
    #pragma unroll
    for (int ui = 0; ui < 5; ++ui) {
      const int u = wave + ui * 8;
      if (u < 36) {
        const int rt = u % 6, cc = u / 6;
        const int row = rt * 16 + rl;
        short8v af[6];
        #pragma unroll
        for (int kt = 0; kt < 3; ++kt)
          packFrag(&sm[OFF_BV + row * LDA + kt * 32 + q * 8], af[kt]);
        #pragma unroll
        for (int kt = 3; kt < 6; ++kt)
          packFrag(&sm[OFF_H + row * LDA + (kt - 3) * 32 + q * 8], af[kt]);
        float4v ga[4] = {{0,0,0,0},{0,0,0,0},{0,0,0,0},{0,0,0,0}};
        #pragma unroll
        for (int gate = 0; gate < 4; ++gate) {
          const int ct = gate * 6 + cc;
          #pragma unroll
          for (int kt = 0; kt < 6; ++kt) {
            const int base = (kt < 3) ? W_IH : W_HH;
            const short* bp = WS + base + (ct * 3 + (kt % 3)) * 512 + lane * 8;
            const short8v bh = *reinterpret_cast<const short8v*>(bp);
            const short8v bl = *reinterpret_cast<const short8v*>(bp + 72 * 512);
            ga[gate] = mfma2(af[kt], bh, bl, ga[gate]);
          }
        }
        const int col = cc * 16 + rl;
        #pragma unroll
        for (int j = 0; j < 4; ++j) {
          const float gi = ga[0][j] + bih[col]       + bhh[col];
          const float gf = ga[1][j] + bih[96 + col]  + bhh[96 + col];
          const float gg = ga[2][j] + bih[192 + col] + bhh[192 + col];
          const float go = ga[3][j] + bih[288 + col] + bhh[288 + col];
          const float c2 = sigm(gf) * creg[ui][j] + sigm(gi) * tanh_(gg);
          creg[ui][j] = c2;
          h2r[ui][j] = sigm(go) * tanh_(c2);
        }
      }
    }
    __syncthreads();
    #pragma unroll
    for (int ui = 0; ui < 5; ++ui) {
      const int u = wave + ui * 8;
      if (u < 36) {
        const int rt = u % 6, cc = u / 6;
        #pragma unroll
        for (int j = 0; j < 4; ++j) {
          const int row = rt * 16 + q * 4 + j, col = cc * 16 + rl;
          if (row < NN) sm[OFF_H + row * LDA + col] = h2r[ui][j];
        }
      }
    }
    __syncthreads();

    // phase 8..10: readout
    stage96(sm, OFF_H,  WS, W_R0, 18, 6, r_b0, 1.f, true, false, &sm[OFF_AP], LDA, wave, lane);
    __syncthreads();
    stage96(sm, OFF_AP, WS, W_R1, 18, 6, r_b1, 1.f, true, false, &sm[OFF_BV], LDA, wave, lane);
    __syncthreads();
    if (wave < 3) {  // r2: 96->16 (9 real cols), 3 row-tile-pairs
      const int rtp = wave;
      short8v a2[2][3];
      #pragma unroll
      for (int sub = 0; sub < 2; ++sub) {
        const int row = rtp * 32 + sub * 16 + rl;
        #pragma unroll
        for (int kt = 0; kt < 3; ++kt)
          packFrag(&sm[OFF_BV + row * LDA + kt * 32 + q * 8], a2[sub][kt]);
      }
      float4v a0 = {0,0,0,0}, a1 = {0,0,0,0};
      #pragma unroll
      for (int kt = 0; kt < 3; ++kt) {
        const short* bp = WS + W_R2 + kt * 512 + lane * 8;
        const short8v bh = *reinterpret_cast<const short8v*>(bp);
        const short8v bl = *reinterpret_cast<const short8v*>(bp + 3 * 512);
        a0 = mfma2(a2[0][kt], bh, bl, a0);
        a1 = mfma2(a2[1][kt], bh, bl, a1);
      }
      if (rl < NOUT) {
        float* op = out + ((size_t)it * BATCH + b) * NN * NOUT;
        #pragma unroll
        for (int sub = 0; sub < 2; ++sub)
          #pragma unroll
          for (int j = 0; j < 4; ++j) {
            const int row = rtp * 32 + sub * 16 + q * 4 + j;
            if (row < NN) op[row * NOUT + rl] = (sub ? a1[j] : a0[j]) + r_b2[rl];
          }
      }
    }
    __syncthreads();
  }
}

extern "C" void kernel_launch(void* const* d_in, const int* in_sizes, int n_in,
                              void* d_out, int out_size, void* d_ws, size_t ws_size,
                              hipStream_t stream) {
  (void)in_sizes; (void)n_in; (void)out_size; (void)ws_size;
  const int* grids = (const int*)d_in[0];
  const int* iters = (const int*)d_in[1];
  const float *emb = (const float*)d_in[2],
    *in_w0 = (const float*)d_in[3],  *in_b0 = (const float*)d_in[4],
    *in_b1 = (const float*)d_in[6],  *in_b2 = (const float*)d_in[8],
    *rel_w0 = (const float*)d_in[9],  *rel_b0 = (const float*)d_in[10],
    *rel_w1 = (const float*)d_in[11], *rel_b1 = (const float*)d_in[12],
    *rel_w2 = (const float*)d_in[13], *rel_b2 = (const float*)d_in[14],
    *g_w0 = (const float*)d_in[15], *g_b0 = (const float*)d_in[16],
    *g_w1 = (const float*)d_in[17], *g_b1 = (const float*)d_in[18],
    *g_w2 = (const float*)d_in[19], *g_b2 = (const float*)d_in[20],
    *wih = (const float*)d_in[21], *whh = (const float*)d_in[22],
    *bih = (const float*)d_in[23], *bhh = (const float*)d_in[24],
    *r_w0 = (const float*)d_in[25], *r_b0 = (const float*)d_in[26],
    *r_w1 = (const float*)d_in[27], *r_b1 = (const float*)d_in[28],
    *r_w2 = (const float*)d_in[29], *r_b2 = (const float*)d_in[30],
    *c0 = (const float*)d_in[31];
  short* ws = (short*)d_ws;
  pack_kernel<<<dim3(363), dim3(64), 0, stream>>>(
      rel_w0, rel_w1, rel_w2, g_w0, g_w1, g_w2, wih, whh,
      r_w0, r_w1, r_w2, (const float*)d_in[5], (const float*)d_in[7], ws);
  rrn_kernel<<<dim3(BATCH), dim3(BLOCK), 0, stream>>>(
      grids, iters, emb, in_w0, in_b0, in_b1, in_b2,
      rel_b0, rel_b1, rel_b2, g_b0, g_b1, g_b2,
      bih, bhh, r_b0, r_b1, r_b2, c0, (const short*)ws, (float*)d_out);
}

// Round 9
// 919.698 us; speedup vs baseline: 2.4766x; 2.0925x over previous
//
#include <hip/hip_runtime.h>
#include <hip/hip_bf16.h>
#include <stdint.h>

typedef __attribute__((ext_vector_type(8))) short short8v;  // MFMA bf16 A/B frag (guide §3)
typedef __attribute__((ext_vector_type(4))) float float4v;  // MFMA C/D frag

#define DEVI __device__ __forceinline__

constexpr int BATCH = 256;
constexpr int NN   = 81;
constexpr int HID  = 96;
constexpr int NOUT = 9;
constexpr int BLOCK = 512;
constexpr int LDA = 100;   // LDS f32 row stride: mult of 4 (16B-aligned rows) + bank rotation

// LDS float offsets (frag-read buffers stride LDA; Xg stride 96). Pad-row frag reads
// (rows 81..95) spill into the NEXT region - harmless finite garbage, C rows masked on write.
constexpr int OFF_H  = 0;
constexpr int OFF_AP = 8100;    // 81*100
constexpr int OFF_BV = 16200;
constexpr int OFF_MS = 24300;
constexpr int OFF_XG = 32400;   // 81*96
constexpr int SMEM_F = 40176;   // 160,704 B <= 163,840

// packed weights in d_ws (shorts). Per matrix: hi tiles [(ct*3+kt)*512 + lane*8 + j],
// lo plane at +ntiles*512. ALL source matrices are [K rows][C cols] row-major.
// rel_w0 / g_w0 are 192x96 (K=192): packed as TWO 96x96 halves (rows 0..95 / 96..191).
constexpr int W_REL0A = 0;       // rel_w0 rows 0..95   (self proj)
constexpr int W_REL0B = 18432;   // rel_w0 rows 96..191 (neighbor proj)
constexpr int W_REL1  = 36864;
constexpr int W_REL2  = 55296;
constexpr int W_G0B   = 73728;   // g_w0 rows 96..191
constexpr int W_G1    = 92160;
constexpr int W_G2    = 110592;
constexpr int W_IH    = 129024;  // 96x384, 72 tiles
constexpr int W_HH    = 202752;
constexpr int W_R0    = 276480;
constexpr int W_R1    = 294912;
constexpr int W_R2    = 313344;  // 96x16 (cols 9..15 zero), 3 tiles
constexpr int W_IN1   = 316416;
constexpr int W_IN2   = 334848;
constexpr int W_G0A   = 353280;  // g_w0 rows 0..95 ; end 371,712 shorts = 743,424 B

DEVI float sigm(float x)  { return 1.f / (1.f + __expf(-x)); }
DEVI float tanh_(float x) { return 1.f - 2.f / (__expf(2.f * x) + 1.f); }

// weight split: hi = truncate-to-bf16, lo = RNE-bf16(x - hi): combined rel err ~2^-16
DEVI short bfhi(float x) { union { float f; unsigned u; } v; v.f = x; return (short)(v.u >> 16); }
DEVI float fromBits(short s) { union { unsigned u; float f; } v; v.u = ((unsigned)(unsigned short)s) << 16; return v.f; }
DEVI short bfrne(float x) {
  union { float f; unsigned u; } v; v.f = x;
  unsigned r = v.u + 0x7fffu + ((v.u >> 16) & 1u);
  return (short)(r >> 16);
}
DEVI void split1(float x, short& h, short& l) { h = bfhi(x); l = bfrne(x - fromBits(h)); }

// A-side: SINGLE RNE bf16 (v3-verified precision regime)
DEVI void packFrag(const float* p, short8v& v) {
  const float4 a = *reinterpret_cast<const float4*>(p);
  const float4 b = *reinterpret_cast<const float4*>(p + 4);
  v[0] = bfrne(a.x); v[1] = bfrne(a.y); v[2] = bfrne(a.z); v[3] = bfrne(a.w);
  v[4] = bfrne(b.x); v[5] = bfrne(b.y); v[6] = bfrne(b.z); v[7] = bfrne(b.w);
}
// t0 = relu(Ap_row + Bv_row), RNE-packed
DEVI void packFragPair(const float* ap, const float* bp, short8v& v) {
  const float4 a0 = *reinterpret_cast<const float4*>(ap);
  const float4 a1 = *reinterpret_cast<const float4*>(ap + 4);
  const float4 b0 = *reinterpret_cast<const float4*>(bp);
  const float4 b1 = *reinterpret_cast<const float4*>(bp + 4);
  v[0] = bfrne(fmaxf(a0.x + b0.x, 0.f)); v[1] = bfrne(fmaxf(a0.y + b0.y, 0.f));
  v[2] = bfrne(fmaxf(a0.z + b0.z, 0.f)); v[3] = bfrne(fmaxf(a0.w + b0.w, 0.f));
  v[4] = bfrne(fmaxf(a1.x + b1.x, 0.f)); v[5] = bfrne(fmaxf(a1.y + b1.y, 0.f));
  v[6] = bfrne(fmaxf(a1.z + b1.z, 0.f)); v[7] = bfrne(fmaxf(a1.w + b1.w, 0.f));
}

// acc += A * (Wh + Wl): 2 MFMAs
DEVI float4v mfma2(short8v a, short8v bh, short8v bl, float4v acc) {
  acc = __builtin_amdgcn_mfma_f32_16x16x32_bf16(a, bh, acc, 0, 0, 0);
  acc = __builtin_amdgcn_mfma_f32_16x16x32_bf16(a, bl, acc, 0, 0, 0);
  return acc;
}

// e-th Sudoku peer of node n (order-free: message sum is permutation-invariant)
DEVI int nbr_of(int n, int e) {
  const int r = n / 9, c = n - 9 * r;
  if (e < 8)  { int cc = c + 1 + e;  if (cc >= 9) cc -= 9; return r * 9 + cc; }
  if (e < 16) { int rr = r + e - 7;  if (rr >= 9) rr -= 9; return rr * 9 + c; }
  const int q = e - 16, dr = 1 + (q >> 1), dc = 1 + (q & 1);
  const int rm = r % 3, cm = c % 3;
  int rr = r - rm + rm + dr; rr -= (rm + dr >= 3) ? 3 : 0;
  int cc = c - cm + cm + dc; cc -= (cm + dc >= 3) ? 3 : 0;
  return rr * 9 + cc;
}

// ---------------- weight pack kernel ----------------
__global__ __launch_bounds__(64)
void pack_kernel(const float* rel_w0, const float* rel_w1, const float* rel_w2,
                 const float* g_w0, const float* g_w1, const float* g_w2,
                 const float* wih, const float* whh,
                 const float* r_w0, const float* r_w1, const float* r_w2,
                 const float* in_w1, const float* in_w2, short* ws)
{
  const int lane = threadIdx.x;
  const int blk = blockIdx.x;
  const int starts[16] = {0,18,36,54,72,90,108,126,198,270,288,306,309,327,345,363};
  int mi = 0;
  while (blk >= starts[mi + 1]) ++mi;
  const int tt = blk - starts[mi];
  const int ntile = starts[mi + 1] - starts[mi];
  const float* src; int C = 96, row0 = 0, off;
  switch (mi) {
    case 0:  src = rel_w0; off = W_REL0A; break;            // rel_w0[0:96]   (192x96!)
    case 1:  src = rel_w0; row0 = 96; off = W_REL0B; break; // rel_w0[96:192]
    case 2:  src = rel_w1; off = W_REL1; break;
    case 3:  src = rel_w2; off = W_REL2; break;
    case 4:  src = g_w0; row0 = 96; off = W_G0B; break;
    case 5:  src = g_w1; off = W_G1; break;
    case 6:  src = g_w2; off = W_G2; break;
    case 7:  src = wih; C = 384; off = W_IH; break;
    case 8:  src = whh; C = 384; off = W_HH; break;
    case 9:  src = r_w0; off = W_R0; break;
    case 10: src = r_w1; off = W_R1; break;
    case 11: src = r_w2; C = 9; off = W_R2; break;
    case 12: src = in_w1; off = W_IN1; break;
    case 13: src = in_w2; off = W_IN2; break;
    default: src = g_w0; off = W_G0A; break;
  }
  const int kt = tt % 3, ct = tt / 3;
  const int q = lane >> 4, r = lane & 15;
  const int c = ct * 16 + r;
  short* hd = ws + off + tt * 512 + lane * 8;
  short* ld = hd + ntile * 512;
  #pragma unroll
  for (int j = 0; j < 8; ++j) {
    const int k = row0 + kt * 32 + q * 8 + j;
    float w = (c < C) ? src[k * C + c] : 0.f;
    short h, l; split1(w, h, l);
    hd[j] = h; ld[j] = l;
  }
}

// ---------------- generic node-GEMM stage: dst[81 x (CT*16)] = act(A[81x96] @ W + ...) ----------------
DEVI void stage96(float* sm, int aOff, const short* WS, int wOff, int wTiles, int CT,
                  const float* bias, float bscale, bool relu, bool xgAdd,
                  float* dst, int dstLD, int wave, int lane)
{
  const int rl = lane & 15, q = lane >> 4;
  const int plane = wTiles * 512;
  #pragma unroll 1
  for (int t = wave; t < 3 * CT; t += 8) {
    const int rtp = t % 3, ct = t / 3;
    short8v a2[2][3];
    #pragma unroll
    for (int sub = 0; sub < 2; ++sub) {
      const int row = rtp * 32 + sub * 16 + rl;
      const float* ap = &sm[aOff + row * LDA + q * 8];
      #pragma unroll
      for (int kt = 0; kt < 3; ++kt) packFrag(ap + kt * 32, a2[sub][kt]);
    }
    float4v acc0 = {0.f, 0.f, 0.f, 0.f}, acc1 = {0.f, 0.f, 0.f, 0.f};
    #pragma unroll
    for (int kt = 0; kt < 3; ++kt) {
      const short* bp = WS + wOff + (ct * 3 + kt) * 512 + lane * 8;
      const short8v bh = *reinterpret_cast<const short8v*>(bp);
      const short8v bl = *reinterpret_cast<const short8v*>(bp + plane);
      acc0 = mfma2(a2[0][kt], bh, bl, acc0);
      acc1 = mfma2(a2[1][kt], bh, bl, acc1);
    }
    const int col = ct * 16 + rl;
    #pragma unroll
    for (int sub = 0; sub < 2; ++sub) {
      #pragma unroll
      for (int j = 0; j < 4; ++j) {
        const int row = rtp * 32 + sub * 16 + q * 4 + j;
        if (row < NN) {
          float v = sub ? acc1[j] : acc0[j];
          if (bias)  v += bias[col] * bscale;
          if (xgAdd) v += sm[OFF_XG + row * 96 + col];
          if (relu)  v = fmaxf(v, 0.f);
          dst[row * dstLD + col] = v;
        }
      }
    }
  }
}

// ---------------- main kernel ----------------
__global__ __launch_bounds__(BLOCK) __attribute__((amdgpu_waves_per_eu(1, 2)))
void rrn_kernel(const int* __restrict__ grids, const int* __restrict__ itersp,
                const float* __restrict__ emb, const float* __restrict__ in_w0,
                const float* __restrict__ in_b0, const float* __restrict__ in_b1,
                const float* __restrict__ in_b2,
                const float* __restrict__ rel_b0, const float* __restrict__ rel_b1,
                const float* __restrict__ rel_b2,
                const float* __restrict__ g_b0, const float* __restrict__ g_b1,
                const float* __restrict__ g_b2,
                const float* __restrict__ bih, const float* __restrict__ bhh,
                const float* __restrict__ r_b0, const float* __restrict__ r_b1,
                const float* __restrict__ r_b2,
                const float* __restrict__ c0, const short* __restrict__ WS,
                float* __restrict__ out)
{
  __shared__ float sm[SMEM_F];
  const int b = blockIdx.x, tid = threadIdx.x;
  const int wave = tid >> 6, lane = tid & 63;
  const int rl = lane & 15, q = lane >> 4;
  const int iters = itersp[0];

  // LSTM cell state in registers, cc-per-wave mapping: wave w<6 owns col-tile cc=w.
  // creg[rt][j] = c[n = rt*16 + q*4 + j][col = wave*16 + rl]
  float creg[6][4];
  #pragma unroll
  for (int rt = 0; rt < 6; ++rt)
    #pragma unroll
    for (int j = 0; j < 4; ++j) creg[rt][j] = 0.f;
  if (wave < 6) {
    #pragma unroll
    for (int rt = 0; rt < 6; ++rt) {
      #pragma unroll
      for (int j = 0; j < 4; ++j) {
        const int n = rt * 16 + q * 4 + j, col = wave * 16 + rl;
        creg[rt][j] = (n < NN) ? c0[(size_t)b * NN * HID + n * HID + col] : 0.f;
      }
    }
  }

  // ---- prologue: embed L0 (VALU, K=16) then MFMA stages ----
  for (int t = tid; t < NN * HID; t += BLOCK) {
    const int n = t / HID, col = t - n * HID;
    const int g = grids[b * NN + n];
    float acc = in_b0[col];
    #pragma unroll
    for (int k = 0; k < 16; ++k) acc += emb[g * 16 + k] * in_w0[k * HID + col];
    sm[OFF_AP + n * LDA + col] = fmaxf(acc, 0.f);
  }
  __syncthreads();
  stage96(sm, OFF_AP, WS, W_IN1, 18, 6, in_b1, 1.f, true,  false, &sm[OFF_BV], LDA, wave, lane);
  __syncthreads();
  stage96(sm, OFF_BV, WS, W_IN2, 18, 6, in_b2, 1.f, false, false, &sm[OFF_H],  LDA, wave, lane);
  __syncthreads();
  stage96(sm, OFF_H,  WS, W_G0A, 18, 6, g_b0,  1.f, false, false, &sm[OFF_XG], 96,  wave, lane);
  __syncthreads();

  for (int it = 0; it < iters; ++it) {
    // phase 1: zero Msum; Ap = h@rel_w0[0:96] + rel_b0 ; Bv = h@rel_w0[96:192]
    for (int i = tid; i < 8100; i += BLOCK) sm[OFF_MS + i] = 0.f;
    stage96(sm, OFF_H, WS, W_REL0A, 18, 6, rel_b0, 1.f, false, false, &sm[OFF_AP], LDA, wave, lane);
    stage96(sm, OFF_H, WS, W_REL0B, 18, 6, nullptr, 0.f, false, false, &sm[OFF_BV], LDA, wave, lane);
    __syncthreads();

    // phase 2: pair GEMM, 51 wave-private groups of 32 pair-rows
    #pragma unroll 1
    for (int g2 = wave; g2 < 51; g2 += 8) {
      short8v a2[2][3];
      #pragma unroll
      for (int sub = 0; sub < 2; ++sub) {
        const int row = g2 * 32 + sub * 16 + rl;
        if (row < 1620) {
          const int n = row / 20, e = row - 20 * n, m = nbr_of(n, e);
          const float* ap = &sm[OFF_AP + n * LDA + q * 8];
          const float* bp = &sm[OFF_BV + m * LDA + q * 8];
          #pragma unroll
          for (int kt = 0; kt < 3; ++kt)
            packFragPair(ap + kt * 32, bp + kt * 32, a2[sub][kt]);
        } else {
          const short8v z = {0,0,0,0,0,0,0,0};
          #pragma unroll
          for (int kt = 0; kt < 3; ++kt) a2[sub][kt] = z;
        }
      }
      #pragma unroll 1
      for (int ct = 0; ct < 6; ++ct) {
        const float rb1c = rel_b1[ct * 16 + rl];   // L1-resident
        float4v acc0 = {0,0,0,0}, acc1 = {0,0,0,0};
        #pragma unroll
        for (int kt = 0; kt < 3; ++kt) {
          const short* bp = WS + W_REL1 + (ct * 3 + kt) * 512 + lane * 8;
          const short8v bh = *reinterpret_cast<const short8v*>(bp);
          const short8v bl = *reinterpret_cast<const short8v*>(bp + 18 * 512);
          acc0 = mfma2(a2[0][kt], bh, bl, acc0);
          acc1 = mfma2(a2[1][kt], bh, bl, acc1);
        }
        const int col = ct * 16 + rl;
        #pragma unroll
        for (int sub = 0; sub < 2; ++sub) {
          const int r0 = g2 * 32 + sub * 16 + q * 4;  // 4 rows, same node (20%4==0)
          if (r0 < 1620) {
            const int node = r0 / 20;
            const float4v a = sub ? acc1 : acc0;
            const float s = fmaxf(a[0] + rb1c, 0.f) + fmaxf(a[1] + rb1c, 0.f)
                          + fmaxf(a[2] + rb1c, 0.f) + fmaxf(a[3] + rb1c, 0.f);
            atomicAdd(&sm[OFF_MS + node * LDA + col], s);
          }
        }
        __builtin_amdgcn_sched_barrier(0);  // no cross-ct load hoisting
      }
    }
    __syncthreads();

    // phase 3..6: M' -> g0 -> g1 -> x_in
    stage96(sm, OFF_MS, WS, W_REL2, 18, 6, rel_b2, 20.f, false, false, &sm[OFF_AP], LDA, wave, lane);
    __syncthreads();
    stage96(sm, OFF_AP, WS, W_G0B, 18, 6, nullptr, 0.f, true, true,  &sm[OFF_BV], LDA, wave, lane);
    __syncthreads();
    stage96(sm, OFF_BV, WS, W_G1, 18, 6, g_b1, 1.f, true,  false, &sm[OFF_AP], LDA, wave, lane);
    __syncthreads();
    stage96(sm, OFF_AP, WS, W_G2, 18, 6, g_b2, 1.f, false, false, &sm[OFF_BV], LDA, wave, lane);
    __syncthreads();

    // phase 7: LSTM, cc-per-wave (waves 0-5 own cc=wave; weight tiles wave-private,
    // L1-hot across the 6 rt sweeps; sched_barriers cap transient load regs).
    // gates = x_in@wih + h@whh + (bih+bhh); h2 -> AP (dead buffer), then copy to H.
    if (wave < 6) {
      const int colh = wave * 16 + rl;
      #pragma unroll
      for (int rt = 0; rt < 6; ++rt) {
        const int row = rt * 16 + rl;
        short8v af[6];
        #pragma unroll
        for (int kt = 0; kt < 3; ++kt)
          packFrag(&sm[OFF_BV + row * LDA + kt * 32 + q * 8], af[kt]);
        #pragma unroll
        for (int kt = 3; kt < 6; ++kt)
          packFrag(&sm[OFF_H + row * LDA + (kt - 3) * 32 + q * 8], af[kt]);
        float4v ga[4];
        #pragma unroll
        for (int gate = 0; gate < 4; ++gate) {
          const int ct = gate * 6 + wave;
          float4v acc = {0.f, 0.f, 0.f, 0.f};
          #pragma unroll
          for (int kt = 0; kt < 3; ++kt) {
            const short* bp = WS + W_IH + (ct * 3 + kt) * 512 + lane * 8;
            acc = mfma2(af[kt], *reinterpret_cast<const short8v*>(bp),
                        *reinterpret_cast<const short8v*>(bp + 72 * 512), acc);
          }
          __builtin_amdgcn_sched_barrier(0);
          #pragma unroll
          for (int kt = 3; kt < 6; ++kt) {
            const short* bp = WS + W_HH + (ct * 3 + kt - 3) * 512 + lane * 8;
            acc = mfma2(af[kt], *reinterpret_cast<const short8v*>(bp),
                        *reinterpret_cast<const short8v*>(bp + 72 * 512), acc);
          }
          ga[gate] = acc;
          __builtin_amdgcn_sched_barrier(0);
        }
        #pragma unroll
        for (int j = 0; j < 4; ++j) {
          const int n = rt * 16 + q * 4 + j;
          const float gi = ga[0][j] + bih[colh]       + bhh[colh];
          const float gf = ga[1][j] + bih[96 + colh]  + bhh[96 + colh];
          const float gg = ga[2][j] + bih[192 + colh] + bhh[192 + colh];
          const float go = ga[3][j] + bih[288 + colh] + bhh[288 + colh];
          const float c2 = sigm(gf) * creg[rt][j] + sigm(gi) * tanh_(gg);
          creg[rt][j] = c2;
          if (n < NN) sm[OFF_AP + n * LDA + colh] = sigm(go) * tanh_(c2);
        }
      }
    }
    __syncthreads();
    for (int i = tid; i < 8100; i += BLOCK) sm[OFF_H + i] = sm[OFF_AP + i];  // h <- h2
    __syncthreads();

    // phase 8..10: readout
    stage96(sm, OFF_H,  WS, W_R0, 18, 6, r_b0, 1.f, true, false, &sm[OFF_AP], LDA, wave, lane);
    __syncthreads();
    stage96(sm, OFF_AP, WS, W_R1, 18, 6, r_b1, 1.f, true, false, &sm[OFF_BV], LDA, wave, lane);
    __syncthreads();
    if (wave < 3) {  // r2: 96->16 (9 real cols), 3 row-tile-pairs
      const int rtp = wave;
      short8v a2[2][3];
      #pragma unroll
      for (int sub = 0; sub < 2; ++sub) {
        const int row = rtp * 32 + sub * 16 + rl;
        #pragma unroll
        for (int kt = 0; kt < 3; ++kt)
          packFrag(&sm[OFF_BV + row * LDA + kt * 32 + q * 8], a2[sub][kt]);
      }
      float4v a0 = {0,0,0,0}, a1 = {0,0,0,0};
      #pragma unroll
      for (int kt = 0; kt < 3; ++kt) {
        const short* bp = WS + W_R2 + kt * 512 + lane * 8;
        const short8v bh = *reinterpret_cast<const short8v*>(bp);
        const short8v bl = *reinterpret_cast<const short8v*>(bp + 3 * 512);
        a0 = mfma2(a2[0][kt], bh, bl, a0);
        a1 = mfma2(a2[1][kt], bh, bl, a1);
      }
      if (rl < NOUT) {
        float* op = out + ((size_t)it * BATCH + b) * NN * NOUT;
        #pragma unroll
        for (int sub = 0; sub < 2; ++sub)
          #pragma unroll
          for (int j = 0; j < 4; ++j) {
            const int row = rtp * 32 + sub * 16 + q * 4 + j;
            if (row < NN) op[row * NOUT + rl] = (sub ? a1[j] : a0[j]) + r_b2[rl];
          }
      }
    }
    __syncthreads();
  }
}

extern "C" void kernel_launch(void* const* d_in, const int* in_sizes, int n_in,
                              void* d_out, int out_size, void* d_ws, size_t ws_size,
                              hipStream_t stream) {
  (void)in_sizes; (void)n_in; (void)out_size; (void)ws_size;
  const int* grids = (const int*)d_in[0];
  const int* iters = (const int*)d_in[1];
  const float *emb = (const float*)d_in[2],
    *in_w0 = (const float*)d_in[3],  *in_b0 = (const float*)d_in[4],
    *in_b1 = (const float*)d_in[6],  *in_b2 = (const float*)d_in[8],
    *rel_w0 = (const float*)d_in[9],  *rel_b0 = (const float*)d_in[10],
    *rel_w1 = (const float*)d_in[11], *rel_b1 = (const float*)d_in[12],
    *rel_w2 = (const float*)d_in[13], *rel_b2 = (const float*)d_in[14],
    *g_w0 = (const float*)d_in[15], *g_b0 = (const float*)d_in[16],
    *g_w1 = (const float*)d_in[17], *g_b1 = (const float*)d_in[18],
    *g_w2 = (const float*)d_in[19], *g_b2 = (const float*)d_in[20],
    *wih = (const float*)d_in[21], *whh = (const float*)d_in[22],
    *bih = (const float*)d_in[23], *bhh = (const float*)d_in[24],
    *r_w0 = (const float*)d_in[25], *r_b0 = (const float*)d_in[26],
    *r_w1 = (const float*)d_in[27], *r_b1 = (const float*)d_in[28],
    *r_w2 = (const float*)d_in[29], *r_b2 = (const float*)d_in[30],
    *c0 = (const float*)d_in[31];
  short* ws = (short*)d_ws;
  pack_kernel<<<dim3(363), dim3(64), 0, stream>>>(
      rel_w0, rel_w1, rel_w2, g_w0, g_w1, g_w2, wih, whh,
      r_w0, r_w1, r_w2, (const float*)d_in[5], (const float*)d_in[7], ws);
  rrn_kernel<<<dim3(BATCH), dim3(BLOCK), 0, stream>>>(
      grids, iters, emb, in_w0, in_b0, in_b1, in_b2,
      rel_b0, rel_b1, rel_b2, g_b0, g_b1, g_b2,
      bih, bhh, r_b0, r_b1, r_b2, c0, (const short*)ws, (float*)d_out);
}

// Round 10
// 823.358 us; speedup vs baseline: 2.7664x; 1.1170x over previous
//
#include <hip/hip_runtime.h>
#include <hip/hip_bf16.h>
#include <stdint.h>

typedef __attribute__((ext_vector_type(8))) short short8v;  // MFMA bf16 A/B frag
typedef __attribute__((ext_vector_type(4))) float float4v;  // MFMA C/D frag

#define DEVI __device__ __forceinline__

constexpr int BATCH = 256;
constexpr int NN   = 81;
constexpr int HID  = 96;
constexpr int NOUT = 9;
constexpr int BLOCK = 512;
constexpr int LDA = 100;   // f32 LDS row stride (floats): 16B-aligned rows, conflict-free 16-lane
constexpr int LDB = 104;   // bf16 LDS row stride (shorts): 208B = 16B-aligned, 2-way-free banks

// LDS float offsets. bf16 buffers (H0/H1, B1≡AP, B2≡MS) hold 81x104 shorts; fragment
// reads touch pad rows 81..95 which SPILL into the next region - harmless garbage,
// C rows masked at write. Last buffer (BV) is only ever read at node rows <= 80.
constexpr int OFF_XG = 0;        // f32 81x96   Xg (iteration-invariant)
constexpr int OFF_H0 = 7776;     // bf16 h buffer A
constexpr int OFF_H1 = 11988;    // bf16 h buffer B
constexpr int OFF_MS = 16200;    // f32 81x100 Msum (atomics)  / B2 bf16 scratch
constexpr int OFF_AP = 24300;    // f32 81x100 self-proj       / B1 bf16 scratch
constexpr int OFF_BV = 32400;    // f32 81x100 neighbor-proj
constexpr int SMEM_F = 40500;    // 162,000 B <= 163,840

// packed weights in d_ws (shorts): hi tiles [(ct*3+kt)*512 + lane*8 + j], lo at +ntiles*512.
constexpr int W_REL0A = 0;       // rel_w0 rows 0..95   (self proj; 192x96 source)
constexpr int W_REL0B = 18432;   // rel_w0 rows 96..191 (neighbor proj)
constexpr int W_REL1  = 36864;
constexpr int W_REL2  = 55296;
constexpr int W_G0B   = 73728;   // g_w0 rows 96..191
constexpr int W_G1    = 92160;
constexpr int W_G2    = 110592;
constexpr int W_IH    = 129024;  // 96x384, 72 tiles
constexpr int W_HH    = 202752;
constexpr int W_R0    = 276480;
constexpr int W_R1    = 294912;
constexpr int W_R2    = 313344;  // 96x16 (cols 9..15 zero)
constexpr int W_IN1   = 316416;
constexpr int W_IN2   = 334848;
constexpr int W_G0A   = 353280;  // g_w0 rows 0..95 ; end 371,712 shorts = 743,424 B

DEVI float sigm(float x)  { return 1.f / (1.f + __expf(-x)); }
DEVI float tanh_(float x) { return 1.f - 2.f / (__expf(2.f * x) + 1.f); }

DEVI short bfhi(float x) { union { float f; unsigned u; } v; v.f = x; return (short)(v.u >> 16); }
DEVI float fromBits(short s) { union { unsigned u; float f; } v; v.u = ((unsigned)(unsigned short)s) << 16; return v.f; }
DEVI short bfrne(float x) {
  union { float f; unsigned u; } v; v.f = x;
  unsigned r = v.u + 0x7fffu + ((v.u >> 16) & 1u);
  return (short)(r >> 16);
}
DEVI void split1(float x, short& h, short& l) { h = bfhi(x); l = bfrne(x - fromBits(h)); }

// f32 LDS row -> RNE bf16 fragment (only used for f32-resident buffers: MS, prologue AP)
DEVI void packFrag(const float* p, short8v& v) {
  const float4 a = *reinterpret_cast<const float4*>(p);
  const float4 b = *reinterpret_cast<const float4*>(p + 4);
  v[0] = bfrne(a.x); v[1] = bfrne(a.y); v[2] = bfrne(a.z); v[3] = bfrne(a.w);
  v[4] = bfrne(b.x); v[5] = bfrne(b.y); v[6] = bfrne(b.z); v[7] = bfrne(b.w);
}
// t0 = relu(Ap_row + Bv_row), RNE-packed (per-pair, f32 inputs)
DEVI void packFragPair(const float* ap, const float* bp, short8v& v) {
  const float4 a0 = *reinterpret_cast<const float4*>(ap);
  const float4 a1 = *reinterpret_cast<const float4*>(ap + 4);
  const float4 b0 = *reinterpret_cast<const float4*>(bp);
  const float4 b1 = *reinterpret_cast<const float4*>(bp + 4);
  v[0] = bfrne(fmaxf(a0.x + b0.x, 0.f)); v[1] = bfrne(fmaxf(a0.y + b0.y, 0.f));
  v[2] = bfrne(fmaxf(a0.z + b0.z, 0.f)); v[3] = bfrne(fmaxf(a0.w + b0.w, 0.f));
  v[4] = bfrne(fmaxf(a1.x + b1.x, 0.f)); v[5] = bfrne(fmaxf(a1.y + b1.y, 0.f));
  v[6] = bfrne(fmaxf(a1.z + b1.z, 0.f)); v[7] = bfrne(fmaxf(a1.w + b1.w, 0.f));
}

// acc += A * (Wh + Wl): 2 MFMAs (weights split hi/lo ~2^-16; activations single RNE bf16)
DEVI float4v mfma2(short8v a, short8v bh, short8v bl, float4v acc) {
  acc = __builtin_amdgcn_mfma_f32_16x16x32_bf16(a, bh, acc, 0, 0, 0);
  acc = __builtin_amdgcn_mfma_f32_16x16x32_bf16(a, bl, acc, 0, 0, 0);
  return acc;
}

// e-th Sudoku peer of node n (order-free: message sum is permutation-invariant)
DEVI int nbr_of(int n, int e) {
  const int r = n / 9, c = n - 9 * r;
  if (e < 8)  { int cc = c + 1 + e;  if (cc >= 9) cc -= 9; return r * 9 + cc; }
  if (e < 16) { int rr = r + e - 7;  if (rr >= 9) rr -= 9; return rr * 9 + c; }
  const int q = e - 16, dr = 1 + (q >> 1), dc = 1 + (q & 1);
  const int rm = r % 3, cm = c % 3;
  int rr = r - rm + rm + dr; rr -= (rm + dr >= 3) ? 3 : 0;
  int cc = c - cm + cm + dc; cc -= (cm + dc >= 3) ? 3 : 0;
  return rr * 9 + cc;
}

// ---------------- weight pack kernel ----------------
__global__ __launch_bounds__(64)
void pack_kernel(const float* rel_w0, const float* rel_w1, const float* rel_w2,
                 const float* g_w0, const float* g_w1, const float* g_w2,
                 const float* wih, const float* whh,
                 const float* r_w0, const float* r_w1, const float* r_w2,
                 const float* in_w1, const float* in_w2, short* ws)
{
  const int lane = threadIdx.x;
  const int blk = blockIdx.x;
  const int starts[16] = {0,18,36,54,72,90,108,126,198,270,288,306,309,327,345,363};
  int mi = 0;
  while (blk >= starts[mi + 1]) ++mi;
  const int tt = blk - starts[mi];
  const int ntile = starts[mi + 1] - starts[mi];
  const float* src; int C = 96, row0 = 0, off;
  switch (mi) {
    case 0:  src = rel_w0; off = W_REL0A; break;
    case 1:  src = rel_w0; row0 = 96; off = W_REL0B; break;
    case 2:  src = rel_w1; off = W_REL1; break;
    case 3:  src = rel_w2; off = W_REL2; break;
    case 4:  src = g_w0; row0 = 96; off = W_G0B; break;
    case 5:  src = g_w1; off = W_G1; break;
    case 6:  src = g_w2; off = W_G2; break;
    case 7:  src = wih; C = 384; off = W_IH; break;
    case 8:  src = whh; C = 384; off = W_HH; break;
    case 9:  src = r_w0; off = W_R0; break;
    case 10: src = r_w1; off = W_R1; break;
    case 11: src = r_w2; C = 9; off = W_R2; break;
    case 12: src = in_w1; off = W_IN1; break;
    case 13: src = in_w2; off = W_IN2; break;
    default: src = g_w0; off = W_G0A; break;
  }
  const int kt = tt % 3, ct = tt / 3;
  const int q = lane >> 4, r = lane & 15;
  const int c = ct * 16 + r;
  short* hd = ws + off + tt * 512 + lane * 8;
  short* ld = hd + ntile * 512;
  #pragma unroll
  for (int j = 0; j < 8; ++j) {
    const int k = row0 + kt * 32 + q * 8 + j;
    float w = (c < C) ? src[k * C + c] : 0.f;
    short h, l; split1(w, h, l);
    hd[j] = h; ld[j] = l;
  }
}

// -------- node-GEMM stage: dst[81 x 96] = act(A[81x96] @ W + bias (+Xg)) --------
// ABF: A is bf16 (direct ds_read_b128, zero conversion VALU). OBF: dst is bf16.
template<bool ABF, bool OBF, bool RELU, bool XGADD>
DEVI void stage96(float* sm, int aOff, const short* WS, int wOff, int wTiles,
                  const float* bias, float bscale, int dOff, int dstLDf,
                  int wave, int lane)
{
  const int rl = lane & 15, q = lane >> 4;
  const int plane = wTiles * 512;
  const short* asb = reinterpret_cast<const short*>(sm + aOff);
  short* dsb = reinterpret_cast<short*>(sm + dOff);
  float* dsf = sm + dOff;
  #pragma unroll 1
  for (int t = wave; t < 18; t += 8) {
    const int rtp = t % 3, ct = t / 3;
    short8v a2[2][3];
    #pragma unroll
    for (int sub = 0; sub < 2; ++sub) {
      const int row = rtp * 32 + sub * 16 + rl;
      if (ABF) {
        const short* ap = asb + row * LDB + q * 8;
        #pragma unroll
        for (int kt = 0; kt < 3; ++kt)
          a2[sub][kt] = *reinterpret_cast<const short8v*>(ap + kt * 32);
      } else {
        const float* ap = &sm[aOff + row * LDA + q * 8];
        #pragma unroll
        for (int kt = 0; kt < 3; ++kt) packFrag(ap + kt * 32, a2[sub][kt]);
      }
    }
    float4v acc0 = {0.f, 0.f, 0.f, 0.f}, acc1 = {0.f, 0.f, 0.f, 0.f};
    #pragma unroll
    for (int kt = 0; kt < 3; ++kt) {
      const short* bp = WS + wOff + (ct * 3 + kt) * 512 + lane * 8;
      const short8v bh = *reinterpret_cast<const short8v*>(bp);
      const short8v bl = *reinterpret_cast<const short8v*>(bp + plane);
      acc0 = mfma2(a2[0][kt], bh, bl, acc0);
      acc1 = mfma2(a2[1][kt], bh, bl, acc1);
    }
    const int col = ct * 16 + rl;
    #pragma unroll
    for (int sub = 0; sub < 2; ++sub) {
      #pragma unroll
      for (int j = 0; j < 4; ++j) {
        const int row = rtp * 32 + sub * 16 + q * 4 + j;
        if (row < NN) {
          float v = sub ? acc1[j] : acc0[j];
          if (bias)  v += bias[col] * bscale;
          if (XGADD) v += sm[OFF_XG + row * 96 + col];
          if (RELU)  v = fmaxf(v, 0.f);
          if (OBF) dsb[row * LDB + col] = bfrne(v);
          else     dsf[row * dstLDf + col] = v;
        }
      }
    }
  }
}

// ---------------- main kernel ----------------
__global__ __launch_bounds__(BLOCK) __attribute__((amdgpu_waves_per_eu(1, 2)))
void rrn_kernel(const int* __restrict__ grids, const int* __restrict__ itersp,
                const float* __restrict__ emb, const float* __restrict__ in_w0,
                const float* __restrict__ in_b0, const float* __restrict__ in_b1,
                const float* __restrict__ in_b2,
                const float* __restrict__ rel_b0, const float* __restrict__ rel_b1,
                const float* __restrict__ rel_b2,
                const float* __restrict__ g_b0, const float* __restrict__ g_b1,
                const float* __restrict__ g_b2,
                const float* __restrict__ bih, const float* __restrict__ bhh,
                const float* __restrict__ r_b0, const float* __restrict__ r_b1,
                const float* __restrict__ r_b2,
                const float* __restrict__ c0, const short* __restrict__ WS,
                float* __restrict__ out)
{
  __shared__ float sm[SMEM_F];
  const int b = blockIdx.x, tid = threadIdx.x;
  const int wave = tid >> 6, lane = tid & 63;
  const int rl = lane & 15, q = lane >> 4;
  const int iters = itersp[0];

  // LSTM cell state in registers, cc-per-wave: wave w<6 owns col-tile cc=w.
  float creg[6][4];
  #pragma unroll
  for (int rt = 0; rt < 6; ++rt)
    #pragma unroll
    for (int j = 0; j < 4; ++j) creg[rt][j] = 0.f;
  if (wave < 6) {
    #pragma unroll
    for (int rt = 0; rt < 6; ++rt) {
      #pragma unroll
      for (int j = 0; j < 4; ++j) {
        const int n = rt * 16 + q * 4 + j, col = wave * 16 + rl;
        creg[rt][j] = (n < NN) ? c0[(size_t)b * NN * HID + n * HID + col] : 0.f;
      }
    }
  }

  // ---- prologue: embed L0 (VALU, K=16) -> AP f32, then MFMA stages ----
  for (int t = tid; t < NN * HID; t += BLOCK) {
    const int n = t / HID, col = t - n * HID;
    const int g = grids[b * NN + n];
    float acc = in_b0[col];
    #pragma unroll
    for (int k = 0; k < 16; ++k) acc += emb[g * 16 + k] * in_w0[k * HID + col];
    sm[OFF_AP + n * LDA + col] = fmaxf(acc, 0.f);
  }
  __syncthreads();
  stage96<false, true, true,  false>(sm, OFF_AP, WS, W_IN1, 18, in_b1, 1.f, OFF_MS, 0, wave, lane);
  __syncthreads();
  stage96<true,  true, false, false>(sm, OFF_MS, WS, W_IN2, 18, in_b2, 1.f, OFF_H0, 0, wave, lane);
  __syncthreads();
  stage96<true, false, false, false>(sm, OFF_H0, WS, W_G0A, 18, g_b0,  1.f, OFF_XG, 96, wave, lane);
  __syncthreads();

  for (int it = 0; it < iters; ++it) {
    const int hc = (it & 1) ? OFF_H1 : OFF_H0;   // current h (bf16)
    const int hn = (it & 1) ? OFF_H0 : OFF_H1;   // next h (bf16)

    // phase 1: zero Msum; Ap = h@rel_w0[0:96] + rel_b0 (f32); Bv = h@rel_w0[96:192] (f32)
    for (int i = tid; i < 8100; i += BLOCK) sm[OFF_MS + i] = 0.f;
    stage96<true, false, false, false>(sm, hc, WS, W_REL0A, 18, rel_b0, 1.f, OFF_AP, LDA, wave, lane);
    stage96<true, false, false, false>(sm, hc, WS, W_REL0B, 18, nullptr, 0.f, OFF_BV, LDA, wave, lane);
    __syncthreads();

    // phase 2: pair GEMM, 51 wave-private groups of 32 pair-rows; Msum via LDS atomics
    #pragma unroll 1
    for (int g2 = wave; g2 < 51; g2 += 8) {
      short8v a2[2][3];
      #pragma unroll
      for (int sub = 0; sub < 2; ++sub) {
        const int row = g2 * 32 + sub * 16 + rl;
        if (row < 1620) {
          const int n = row / 20, e = row - 20 * n, m = nbr_of(n, e);
          const float* ap = &sm[OFF_AP + n * LDA + q * 8];
          const float* bp = &sm[OFF_BV + m * LDA + q * 8];
          #pragma unroll
          for (int kt = 0; kt < 3; ++kt)
            packFragPair(ap + kt * 32, bp + kt * 32, a2[sub][kt]);
        } else {
          const short8v z = {0,0,0,0,0,0,0,0};
          #pragma unroll
          for (int kt = 0; kt < 3; ++kt) a2[sub][kt] = z;
        }
      }
      #pragma unroll 1
      for (int ct = 0; ct < 6; ++ct) {
        const float rb1c = rel_b1[ct * 16 + rl];
        float4v acc0 = {0,0,0,0}, acc1 = {0,0,0,0};
        #pragma unroll
        for (int kt = 0; kt < 3; ++kt) {
          const short* bp = WS + W_REL1 + (ct * 3 + kt) * 512 + lane * 8;
          const short8v bh = *reinterpret_cast<const short8v*>(bp);
          const short8v bl = *reinterpret_cast<const short8v*>(bp + 18 * 512);
          acc0 = mfma2(a2[0][kt], bh, bl, acc0);
          acc1 = mfma2(a2[1][kt], bh, bl, acc1);
        }
        const int col = ct * 16 + rl;
        #pragma unroll
        for (int sub = 0; sub < 2; ++sub) {
          const int r0 = g2 * 32 + sub * 16 + q * 4;  // 4 rows, same node (20%4==0)
          if (r0 < 1620) {
            const int node = r0 / 20;
            const float4v a = sub ? acc1 : acc0;
            const float s = fmaxf(a[0] + rb1c, 0.f) + fmaxf(a[1] + rb1c, 0.f)
                          + fmaxf(a[2] + rb1c, 0.f) + fmaxf(a[3] + rb1c, 0.f);
            atomicAdd(&sm[OFF_MS + node * LDA + col], s);
          }
        }
        __builtin_amdgcn_sched_barrier(0);
      }
    }
    __syncthreads();

    // ph3: M' = Msum(f32)@rel_w2 + 20*rel_b2 -> B1 bf16 (in AP region)
    stage96<false, true, false, false>(sm, OFF_MS, WS, W_REL2, 18, rel_b2, 20.f, OFF_AP, 0, wave, lane);
    __syncthreads();
    // ph4: g0 = relu(Xg + M'@g_w0[96:]) -> B2 bf16 (in MS region)
    stage96<true, true, true, true >(sm, OFF_AP, WS, W_G0B, 18, nullptr, 0.f, OFF_MS, 0, wave, lane);
    __syncthreads();
    // ph5: g1 = relu(g0@g_w1 + g_b1) -> B1
    stage96<true, true, true, false>(sm, OFF_MS, WS, W_G1, 18, g_b1, 1.f, OFF_AP, 0, wave, lane);
    __syncthreads();
    // ph6: x_in = g1@g_w2 + g_b2 -> B2
    stage96<true, true, false, false>(sm, OFF_AP, WS, W_G2, 18, g_b2, 1.f, OFF_MS, 0, wave, lane);
    __syncthreads();

    // phase 7: LSTM, cc-per-wave; x_in (B2 bf16) + h (hc bf16) read direct; h2 -> hn bf16
    if (wave < 6) {
      const int colh = wave * 16 + rl;
      const short* xs = reinterpret_cast<const short*>(sm + OFF_MS);
      const short* hs = reinterpret_cast<const short*>(sm + hc);
      short* hnp = reinterpret_cast<short*>(sm + hn);
      #pragma unroll
      for (int rt = 0; rt < 6; ++rt) {
        const int row = rt * 16 + rl;
        short8v af[6];
        #pragma unroll
        for (int kt = 0; kt < 3; ++kt)
          af[kt] = *reinterpret_cast<const short8v*>(xs + row * LDB + kt * 32 + q * 8);
        #pragma unroll
        for (int kt = 3; kt < 6; ++kt)
          af[kt] = *reinterpret_cast<const short8v*>(hs + row * LDB + (kt - 3) * 32 + q * 8);
        float4v ga[4];
        #pragma unroll
        for (int gate = 0; gate < 4; ++gate) {
          const int ct = gate * 6 + wave;
          float4v acc = {0.f, 0.f, 0.f, 0.f};
          #pragma unroll
          for (int kt = 0; kt < 3; ++kt) {
            const short* bp = WS + W_IH + (ct * 3 + kt) * 512 + lane * 8;
            acc = mfma2(af[kt], *reinterpret_cast<const short8v*>(bp),
                        *reinterpret_cast<const short8v*>(bp + 72 * 512), acc);
          }
          __builtin_amdgcn_sched_barrier(0);
          #pragma unroll
          for (int kt = 3; kt < 6; ++kt) {
            const short* bp = WS + W_HH + (ct * 3 + kt - 3) * 512 + lane * 8;
            acc = mfma2(af[kt], *reinterpret_cast<const short8v*>(bp),
                        *reinterpret_cast<const short8v*>(bp + 72 * 512), acc);
          }
          ga[gate] = acc;
          __builtin_amdgcn_sched_barrier(0);
        }
        #pragma unroll
        for (int j = 0; j < 4; ++j) {
          const int n = rt * 16 + q * 4 + j;
          const float gi = ga[0][j] + bih[colh]       + bhh[colh];
          const float gf = ga[1][j] + bih[96 + colh]  + bhh[96 + colh];
          const float gg = ga[2][j] + bih[192 + colh] + bhh[192 + colh];
          const float go = ga[3][j] + bih[288 + colh] + bhh[288 + colh];
          const float c2 = sigm(gf) * creg[rt][j] + sigm(gi) * tanh_(gg);
          creg[rt][j] = c2;
          if (n < NN) hnp[n * LDB + colh] = bfrne(sigm(go) * tanh_(c2));
        }
      }
    }
    __syncthreads();

    // ph8: r0 = relu(h2@r_w0 + r_b0) -> B1 ; ph9: r1 -> B2 ; ph10: out
    stage96<true, true, true, false>(sm, hn, WS, W_R0, 18, r_b0, 1.f, OFF_AP, 0, wave, lane);
    __syncthreads();
    stage96<true, true, true, false>(sm, OFF_AP, WS, W_R1, 18, r_b1, 1.f, OFF_MS, 0, wave, lane);
    __syncthreads();
    if (wave < 3) {  // r2: 96->16 (9 real cols), 3 row-tile-pairs, reads B2 bf16
      const int rtp = wave;
      const short* asb = reinterpret_cast<const short*>(sm + OFF_MS);
      short8v a2[2][3];
      #pragma unroll
      for (int sub = 0; sub < 2; ++sub) {
        const int row = rtp * 32 + sub * 16 + rl;
        #pragma unroll
        for (int kt = 0; kt < 3; ++kt)
          a2[sub][kt] = *reinterpret_cast<const short8v*>(asb + row * LDB + kt * 32 + q * 8);
      }
      float4v a0 = {0,0,0,0}, a1 = {0,0,0,0};
      #pragma unroll
      for (int kt = 0; kt < 3; ++kt) {
        const short* bp = WS + W_R2 + kt * 512 + lane * 8;
        const short8v bh = *reinterpret_cast<const short8v*>(bp);
        const short8v bl = *reinterpret_cast<const short8v*>(bp + 3 * 512);
        a0 = mfma2(a2[0][kt], bh, bl, a0);
        a1 = mfma2(a2[1][kt], bh, bl, a1);
      }
      if (rl < NOUT) {
        float* op = out + ((size_t)it * BATCH + b) * NN * NOUT;
        #pragma unroll
        for (int sub = 0; sub < 2; ++sub)
          #pragma unroll
          for (int j = 0; j < 4; ++j) {
            const int row = rtp * 32 + sub * 16 + q * 4 + j;
            if (row < NN) op[row * NOUT + rl] = (sub ? a1[j] : a0[j]) + r_b2[rl];
          }
      }
    }
    __syncthreads();
  }
}

extern "C" void kernel_launch(void* const* d_in, const int* in_sizes, int n_in,
                              void* d_out, int out_size, void* d_ws, size_t ws_size,
                              hipStream_t stream) {
  (void)in_sizes; (void)n_in; (void)out_size; (void)ws_size;
  const int* grids = (const int*)d_in[0];
  const int* iters = (const int*)d_in[1];
  const float *emb = (const float*)d_in[2],
    *in_w0 = (const float*)d_in[3],  *in_b0 = (const float*)d_in[4],
    *in_b1 = (const float*)d_in[6],  *in_b2 = (const float*)d_in[8],
    *rel_w0 = (const float*)d_in[9],  *rel_b0 = (const float*)d_in[10],
    *rel_w1 = (const float*)d_in[11], *rel_b1 = (const float*)d_in[12],
    *rel_w2 = (const float*)d_in[13], *rel_b2 = (const float*)d_in[14],
    *g_w0 = (const float*)d_in[15], *g_b0 = (const float*)d_in[16],
    *g_w1 = (const float*)d_in[17], *g_b1 = (const float*)d_in[18],
    *g_w2 = (const float*)d_in[19], *g_b2 = (const float*)d_in[20],
    *wih = (const float*)d_in[21], *whh = (const float*)d_in[22],
    *bih = (const float*)d_in[23], *bhh = (const float*)d_in[24],
    *r_w0 = (const float*)d_in[25], *r_b0 = (const float*)d_in[26],
    *r_w1 = (const float*)d_in[27], *r_b1 = (const float*)d_in[28],
    *r_w2 = (const float*)d_in[29], *r_b2 = (const float*)d_in[30],
    *c0 = (const float*)d_in[31];
  short* ws = (short*)d_ws;
  pack_kernel<<<dim3(363), dim3(64), 0, stream>>>(
      rel_w0, rel_w1, rel_w2, g_w0, g_w1, g_w2, wih, whh,
      r_w0, r_w1, r_w2, (const float*)d_in[5], (const float*)d_in[7], ws);
  rrn_kernel<<<dim3(BATCH), dim3(BLOCK), 0, stream>>>(
      grids, iters, emb, in_w0, in_b0, in_b1, in_b2,
      rel_b0, rel_b1, rel_b2, g_b0, g_b1, g_b2,
      bih, bhh, r_b0, r_b1, r_b2, c0, (const short*)ws, (float*)d_out);
}